// Round 5
// baseline (1346.257 us; speedup 1.0000x reference)
//
#include <hip/hip_runtime.h>
#include <math.h>

#define B_N 32768
#define IN_DIM 1024
#define HID 64
#define D_DIM 512
#define P_N 2048

typedef __attribute__((ext_vector_type(8))) short s16x8;
typedef __attribute__((ext_vector_type(4))) short s16x4;
typedef __attribute__((ext_vector_type(4))) float f32x4;

__device__ __forceinline__ unsigned short f2bf(float f) {
    unsigned u = __float_as_uint(f);
    return (unsigned short)((u + 0x7fffu + ((u >> 16) & 1u)) >> 16);
}

// ---------------------------------------------------------------------------
// Pack fp32 [nrows, ncols] row-major -> bf16 MFMA-B-fragment-major.
// frag unit: ((P16*nk32 + K32)*64 + lane) * 8 elems; lane=(row&15)|((k8&3)<<4)
// ---------------------------------------------------------------------------
__global__ __launch_bounds__(256) void k_pack(const float* __restrict__ src,
                                              unsigned short* __restrict__ dst,
                                              int nrows, int nk8) {
    int gid = blockIdx.x * 256 + threadIdx.x;
    if (gid >= nrows * nk8) return;
    int row = gid / nk8, k8 = gid % nk8;
    int K32 = k8 >> 2;
    int lane = (row & 15) | ((k8 & 3) << 4);
    int P16 = row >> 4;
    int nk32 = nk8 >> 2;
    const float* s = src + (size_t)row * (nk8 * 8) + k8 * 8;
    float4 x = *(const float4*)s;
    float4 y = *(const float4*)(s + 4);
    s16x8 o;
    o[0] = (short)f2bf(x.x); o[1] = (short)f2bf(x.y);
    o[2] = (short)f2bf(x.z); o[3] = (short)f2bf(x.w);
    o[4] = (short)f2bf(y.x); o[5] = (short)f2bf(y.y);
    o[6] = (short)f2bf(y.z); o[7] = (short)f2bf(y.w);
    ((s16x8*)dst)[((size_t)P16 * nk32 + K32) * 64 + lane] = o;
}

// ---------------------------------------------------------------------------
// K1 (MFMA): h1 = relu(x @ W0^T + b0)  [B,1024] -> [B,64] bf16 out
// ---------------------------------------------------------------------------
__global__ __launch_bounds__(256, 4) void k_enc1(const float* __restrict__ x,
                                                 const unsigned short* __restrict__ w0p,
                                                 const float* __restrict__ b0,
                                                 unsigned short* __restrict__ h1b) {
    __shared__ s16x8 As[2048];  // 128 rows x 128 bf16, 32 KB
    const int tid = threadIdx.x;
    const int l = tid & 63, wid = tid >> 6;
    const int bm = blockIdx.x * 128;
    const s16x8* w0p8 = (const s16x8*)w0p;

    const int srow = tid >> 1, ssub = tid & 1;
    const int srb = srow * 256, ssw = (srow & 7) << 4;

    const int klane = (l >> 4) << 4;
    const int sw = (l & 7) << 4;
    int aoff[2];
#pragma unroll
    for (int m = 0; m < 2; ++m) aoff[m] = (wid * 32 + m * 16 + (l & 15)) * 256;

    f32x4 acc[2][4];
#pragma unroll
    for (int m = 0; m < 2; ++m)
#pragma unroll
        for (int pf = 0; pf < 4; ++pf) acc[m][pf] = (f32x4)0.f;

    for (int kt = 0; kt < 8; ++kt) {
        const float* src = x + (size_t)(bm + srow) * IN_DIM + kt * 128 + ssub * 64;
#pragma unroll
        for (int it = 0; it < 8; ++it) {
            float4 a = *(const float4*)(src + it * 8);
            float4 b = *(const float4*)(src + it * 8 + 4);
            s16x8 o;
            o[0] = (short)f2bf(a.x); o[1] = (short)f2bf(a.y);
            o[2] = (short)f2bf(a.z); o[3] = (short)f2bf(a.w);
            o[4] = (short)f2bf(b.x); o[5] = (short)f2bf(b.y);
            o[6] = (short)f2bf(b.z); o[7] = (short)f2bf(b.w);
            int kbyte = ssub * 128 + it * 16;
            As[(srb + (kbyte ^ ssw)) >> 4] = o;
        }
        __syncthreads();
#pragma unroll
        for (int K32 = 0; K32 < 4; ++K32) {
            const int Kg = kt * 4 + K32;
            s16x8 b[4];
#pragma unroll
            for (int pf = 0; pf < 4; ++pf) b[pf] = w0p8[((size_t)pf * 32 + Kg) * 64 + l];
            const int kb = (K32 * 64 + klane) ^ sw;
            s16x8 a[2];
#pragma unroll
            for (int m = 0; m < 2; ++m) a[m] = As[(aoff[m] + kb) >> 4];
#pragma unroll
            for (int m = 0; m < 2; ++m)
#pragma unroll
                for (int pf = 0; pf < 4; ++pf)
                    acc[m][pf] = __builtin_amdgcn_mfma_f32_16x16x32_bf16(a[m], b[pf], acc[m][pf], 0, 0, 0);
        }
        __syncthreads();
    }
#pragma unroll
    for (int m = 0; m < 2; ++m)
#pragma unroll
        for (int pf = 0; pf < 4; ++pf) {
            const int c = pf * 16 + (l & 15);
            const float bb = b0[c];
#pragma unroll
            for (int j = 0; j < 4; ++j) {
                const int r = bm + wid * 32 + m * 16 + (l >> 4) * 4 + j;
                h1b[(size_t)r * HID + c] = f2bf(fmaxf(acc[m][pf][j] + bb, 0.f));
            }
        }
}

// ---------------------------------------------------------------------------
// K2 (MFMA): h2 = relu(h1 @ W1^T + b1)  [B,64] -> [B,512] bf16
// 4 waves partition ROWS (16 each); every wave computes ALL 512 cols.
// ---------------------------------------------------------------------------
__global__ __launch_bounds__(256, 4) void k_enc2(const unsigned short* __restrict__ h1b,
                                                 const unsigned short* __restrict__ w1p,
                                                 const float* __restrict__ b1,
                                                 unsigned short* __restrict__ h2b) {
    __shared__ s16x8 As[512];  // 64 rows x 64 bf16, 8 KB
    const int tid = threadIdx.x;
    const int l = tid & 63, wid = tid >> 6;
    const int bm = blockIdx.x * 64;
    const s16x8* w1p8 = (const s16x8*)w1p;

#pragma unroll
    for (int it = 0; it < 2; ++it) {
        int g = tid * 2 + it;
        int row = g >> 3, k8 = g & 7;
        s16x8 v = ((const s16x8*)(h1b + (size_t)(bm + row) * HID))[k8];
        As[(row * 128 + ((k8 * 16) ^ ((row & 7) << 4))) >> 4] = v;
    }
    __syncthreads();

    const int arow = wid * 16 + (l & 15);
    const int sw = (l & 7) << 4;
    const int klane = (l >> 4) << 4;
    s16x8 a[2];
#pragma unroll
    for (int K32 = 0; K32 < 2; ++K32)
        a[K32] = As[(arow * 128 + ((K32 * 64 + klane) ^ sw)) >> 4];

    const int r0 = bm + wid * 16 + (l >> 4) * 4;  // + j
#pragma unroll
    for (int ct = 0; ct < 4; ++ct) {
        f32x4 acc[8];
#pragma unroll
        for (int pf = 0; pf < 8; ++pf) acc[pf] = (f32x4)0.f;
#pragma unroll
        for (int K32 = 0; K32 < 2; ++K32)
#pragma unroll
            for (int pf = 0; pf < 8; ++pf) {
                s16x8 b = w1p8[(((size_t)(ct * 8 + pf)) * 2 + K32) * 64 + l];
                acc[pf] = __builtin_amdgcn_mfma_f32_16x16x32_bf16(a[K32], b, acc[pf], 0, 0, 0);
            }
#pragma unroll
        for (int pf = 0; pf < 8; ++pf) {
            const int c = ct * 128 + pf * 16 + (l & 15);
            const float bb = b1[c];
#pragma unroll
            for (int j = 0; j < 4; ++j)
                h2b[(size_t)(r0 + j) * D_DIM + c] = f2bf(fmaxf(acc[pf][j] + bb, 0.f));
        }
    }
}

// ---------------------------------------------------------------------------
// K3 (MFMA): mu/logvar + reparameterize + KL.
// BM=128, 512 threads (8 waves), A-tile 128 KB dynamic LDS, 1 block/CU.
// Wave wid owns d-cols [wid*64, wid*64+64) via 2 dt-subtiles of 32.
// ---------------------------------------------------------------------------
__global__ __launch_bounds__(512, 2) void k_muvar(const unsigned short* __restrict__ h2b,
                                                  const unsigned short* __restrict__ wmP,
                                                  const unsigned short* __restrict__ wvP,
                                                  const float* __restrict__ bmu,
                                                  const float* __restrict__ bvar,
                                                  const float* __restrict__ eps,
                                                  float* __restrict__ lat,
                                                  float* __restrict__ div_acc) {
    extern __shared__ char smem[];
    s16x8* Hs = (s16x8*)smem;                      // 128 rows x 512 bf16 = 128 KB
    float* red = (float*)(smem + 131072);          // 8 floats
    const int tid = threadIdx.x;
    const int l = tid & 63, wid = tid >> 6;
    const int bm = blockIdx.x * 128;

    {   // stage h2 (bf16) -> swizzled LDS: 512 thr x 16 x 16B
        const int row = tid >> 2, sub = tid & 3;
        const s16x8* src = (const s16x8*)(h2b + (size_t)(bm + row) * D_DIM) + sub * 16;
        const int rb = row * 1024, sw0 = (row & 7) << 4;
#pragma unroll
        for (int it = 0; it < 16; ++it) {
            s16x8 v = src[it];
            int kbyte = sub * 256 + it * 16;
            Hs[(rb + (kbyte ^ sw0)) >> 4] = v;
        }
    }
    __syncthreads();

    const s16x8* wm8 = (const s16x8*)wmP;
    const s16x8* wv8 = (const s16x8*)wvP;
    const int klane = (l >> 4) << 4;
    const int sw = (l & 7) << 4;
    int aoff[8];
#pragma unroll
    for (int m = 0; m < 8; ++m) aoff[m] = (m * 16 + (l & 15)) * 1024;

    float kl = 0.f;
#pragma unroll 1
    for (int dt = 0; dt < 2; ++dt) {
        const int dbase = wid * 64 + dt * 32;
        const int P16 = dbase >> 4;
        f32x4 aM[8][2], aV[8][2];
#pragma unroll
        for (int m = 0; m < 8; ++m)
#pragma unroll
            for (int f = 0; f < 2; ++f) { aM[m][f] = (f32x4)0.f; aV[m][f] = (f32x4)0.f; }

#pragma unroll
        for (int K32 = 0; K32 < 16; ++K32) {
            s16x8 bM[2], bV[2];
#pragma unroll
            for (int f = 0; f < 2; ++f) {
                bM[f] = wm8[((size_t)(P16 + f) * 16 + K32) * 64 + l];
                bV[f] = wv8[((size_t)(P16 + f) * 16 + K32) * 64 + l];
            }
            const int kb = ((K32 << 6) + klane) ^ sw;
#pragma unroll
            for (int m = 0; m < 8; ++m) {
                s16x8 a = Hs[(aoff[m] + kb) >> 4];
#pragma unroll
                for (int f = 0; f < 2; ++f) {
                    aM[m][f] = __builtin_amdgcn_mfma_f32_16x16x32_bf16(a, bM[f], aM[m][f], 0, 0, 0);
                    aV[m][f] = __builtin_amdgcn_mfma_f32_16x16x32_bf16(a, bV[f], aV[m][f], 0, 0, 0);
                }
            }
        }
#pragma unroll
        for (int m = 0; m < 8; ++m)
#pragma unroll
            for (int f = 0; f < 2; ++f) {
                const int d = dbase + f * 16 + (l & 15);
                const float bmv = bmu[d], bvv = bvar[d];
#pragma unroll
                for (int j = 0; j < 4; ++j) {
                    const int row = bm + m * 16 + (l >> 4) * 4 + j;
                    float mu = aM[m][f][j] + bmv;
                    float lv = aV[m][f][j] + bvv;
                    float el = __expf(lv);
                    float la = fmaf(eps[(size_t)row * D_DIM + d], __expf(0.5f * lv), mu);
                    lat[(size_t)row * D_DIM + d] = la;
                    kl += mu * mu + el - lv - 1.f;
                }
            }
    }
    kl *= 0.5f;
#pragma unroll
    for (int m = 1; m < 64; m <<= 1) kl += __shfl_xor(kl, m);
    if (l == 0) red[wid] = kl;
    __syncthreads();
    if (tid == 0) {
        float s = 0.f;
#pragma unroll
        for (int w = 0; w < 8; ++w) s += red[w];
        atomicAdd(div_acc, s);
    }
}

// ---------------------------------------------------------------------------
// K4a: pnorm[p] = sum_d protos[p,d]^2
// ---------------------------------------------------------------------------
__global__ __launch_bounds__(256) void k_pnorm(const float* __restrict__ protos,
                                               float* __restrict__ pnorm) {
    const int p = blockIdx.x * 4 + (threadIdx.x >> 6);
    const int lane = threadIdx.x & 63;
    const float* row = protos + (size_t)p * D_DIM;
    float4 v1 = *(const float4*)(row + lane * 8);
    float4 v2 = *(const float4*)(row + lane * 8 + 4);
    float s = v1.x * v1.x + v1.y * v1.y + v1.z * v1.z + v1.w * v1.w +
              v2.x * v2.x + v2.y * v2.y + v2.z * v2.z + v2.w * v2.w;
#pragma unroll
    for (int m = 1; m < 64; m <<= 1) s += __shfl_xor(s, m);
    if (lane == 0) pnorm[p] = s;
}

// ---------------------------------------------------------------------------
// K4 (MFMA): BM=128, 512 threads (8 waves), A-tile 128 KB dynamic LDS.
// Wave owns 32 protos per ct-tile (8 ct x 256). Per-row sumexp via LDS f32
// atomics; argmax via packed-key LDS atomicMax (monotone in g, tie->min p).
// ---------------------------------------------------------------------------
__device__ __forceinline__ void vq_tile8(const s16x8* __restrict__ Ls,
                                         const s16x8* __restrict__ bpk,
                                         int P16, int l, int klane, int sw,
                                         const int aoff[8], f32x4 acc[8][2]) {
#pragma unroll
    for (int K32 = 0; K32 < 16; ++K32) {
        s16x8 b[2];
#pragma unroll
        for (int pf = 0; pf < 2; ++pf) b[pf] = bpk[((size_t)(P16 + pf) * 16 + K32) * 64 + l];
        const int kb = ((K32 << 6) + klane) ^ sw;
#pragma unroll
        for (int m = 0; m < 8; ++m) {
            s16x8 a = Ls[(aoff[m] + kb) >> 4];
#pragma unroll
            for (int pf = 0; pf < 2; ++pf)
                acc[m][pf] = __builtin_amdgcn_mfma_f32_16x16x32_bf16(a, b[pf], acc[m][pf], 0, 0, 0);
        }
    }
}

__global__ __launch_bounds__(512, 2) void k_vq(const float* __restrict__ lat,
                                               const unsigned short* __restrict__ ppack,
                                               const float* __restrict__ pnorm,
                                               int* __restrict__ idxOut,
                                               float* __restrict__ soft_acc) {
    extern __shared__ char smem[];
    s16x8* Ls = (s16x8*)smem;                          // 128 KB
    float* rowS = (float*)(smem + 131072);             // 128 f32
    unsigned* rowKey = (unsigned*)(smem + 131072 + 512);
    float* invS_l = (float*)(smem + 131072 + 1024);    // 128 f32
    const int tid = threadIdx.x;
    const int l = tid & 63, wid = tid >> 6;
    const int bm = blockIdx.x * 128;

    if (tid < 128) { rowS[tid] = 0.f; rowKey[tid] = 0u; }

    {   // stage latents fp32 -> bf16 swizzled LDS
        const int row = tid >> 2, sub = tid & 3;
        const float* src = lat + (size_t)(bm + row) * D_DIM + sub * 128;
        const int rb = row * 1024, sw0 = (row & 7) << 4;
#pragma unroll
        for (int it = 0; it < 16; ++it) {
            float4 a = *(const float4*)(src + it * 8);
            float4 b = *(const float4*)(src + it * 8 + 4);
            s16x8 o;
            o[0] = (short)f2bf(a.x); o[1] = (short)f2bf(a.y);
            o[2] = (short)f2bf(a.z); o[3] = (short)f2bf(a.w);
            o[4] = (short)f2bf(b.x); o[5] = (short)f2bf(b.y);
            o[6] = (short)f2bf(b.z); o[7] = (short)f2bf(b.w);
            int kbyte = sub * 256 + it * 16;
            Ls[(rb + (kbyte ^ sw0)) >> 4] = o;
        }
    }
    __syncthreads();

    const s16x8* ppk = (const s16x8*)ppack;
    const int klane = (l >> 4) << 4;
    const int sw = (l & 7) << 4;
    int aoff[8];
#pragma unroll
    for (int m = 0; m < 8; ++m) aoff[m] = (m * 16 + (l & 15)) * 1024;

    float s_sum[8][4];
    unsigned mkey[8][4];
#pragma unroll
    for (int m = 0; m < 8; ++m)
#pragma unroll
        for (int j = 0; j < 4; ++j) { s_sum[m][j] = 0.f; mkey[m][j] = 0u; }

    // ---------------- sweep 0: sumexp + packed-key argmax ----------------
#pragma unroll 1
    for (int ct = 0; ct < 8; ++ct) {
        const int pbase = ct * 256 + wid * 32;
        const int P16 = pbase >> 4;
        float pn[2];
#pragma unroll
        for (int pf = 0; pf < 2; ++pf) pn[pf] = pnorm[pbase + pf * 16 + (l & 15)];
        f32x4 acc[8][2];
#pragma unroll
        for (int m = 0; m < 8; ++m)
#pragma unroll
            for (int pf = 0; pf < 2; ++pf) acc[m][pf] = (f32x4)0.f;
        vq_tile8(Ls, ppk, P16, l, klane, sw, aoff, acc);
#pragma unroll
        for (int pf = 0; pf < 2; ++pf) {
            const unsigned ptag = (unsigned)(2047 - (pbase + pf * 16 + (l & 15)));
#pragma unroll
            for (int m = 0; m < 8; ++m)
#pragma unroll
                for (int j = 0; j < 4; ++j) {
                    float g = 2.f * acc[m][pf][j] - pn[pf];
                    s_sum[m][j] += __expf(g);
                    unsigned kk = (__float_as_uint(g + 16.0f) & 0xFFFFF800u) | ptag;
                    mkey[m][j] = mkey[m][j] > kk ? mkey[m][j] : kk;
                }
        }
    }
    // 16-lane reduce, then cross-wave combine via LDS atomics
#pragma unroll
    for (int m = 0; m < 8; ++m)
#pragma unroll
        for (int j = 0; j < 4; ++j) {
            float s = s_sum[m][j];
            unsigned k = mkey[m][j];
#pragma unroll
            for (int d = 1; d < 16; d <<= 1) {
                s += __shfl_xor(s, d);
                unsigned ok = (unsigned)__shfl_xor((int)k, d);
                k = k > ok ? k : ok;
            }
            if ((l & 15) == 0) {
                const int row = m * 16 + (l >> 4) * 4 + j;
                atomicAdd(&rowS[row], s);
                atomicMax(&rowKey[row], k);
            }
        }
    __syncthreads();
    if (tid < 128) {
        invS_l[tid] = 1.f / rowS[tid];
        idxOut[bm + tid] = 2047 - (int)(rowKey[tid] & 2047u);
    }
    __syncthreads();

    float is[8][4];
#pragma unroll
    for (int m = 0; m < 8; ++m)
#pragma unroll
        for (int j = 0; j < 4; ++j) is[m][j] = invS_l[m * 16 + (l >> 4) * 4 + j];

    // ---------------- sweep 1: soft assignment accumulation ----------------
#pragma unroll 1
    for (int ct = 0; ct < 8; ++ct) {
        const int pbase = ct * 256 + wid * 32;
        const int P16 = pbase >> 4;
        float pn[2];
#pragma unroll
        for (int pf = 0; pf < 2; ++pf) pn[pf] = pnorm[pbase + pf * 16 + (l & 15)];
        f32x4 acc[8][2];
#pragma unroll
        for (int m = 0; m < 8; ++m)
#pragma unroll
            for (int pf = 0; pf < 2; ++pf) acc[m][pf] = (f32x4)0.f;
        vq_tile8(Ls, ppk, P16, l, klane, sw, aoff, acc);
        float c[2] = {0.f, 0.f};
#pragma unroll
        for (int m = 0; m < 8; ++m)
#pragma unroll
            for (int pf = 0; pf < 2; ++pf)
#pragma unroll
                for (int j = 0; j < 4; ++j) {
                    float g = 2.f * acc[m][pf][j] - pn[pf];
                    c[pf] += __expf(g) * is[m][j];
                }
#pragma unroll
        for (int pf = 0; pf < 2; ++pf) {
            c[pf] += __shfl_xor(c[pf], 16);
            c[pf] += __shfl_xor(c[pf], 32);
        }
        if (l < 16) {
#pragma unroll
            for (int pf = 0; pf < 2; ++pf) atomicAdd(&soft_acc[pbase + pf * 16 + l], c[pf]);
        }
    }
}

// ---------------------------------------------------------------------------
// K5: out[r,:] = protos[idx[r],:]  (overwrites latents) + vq partial sums
// ---------------------------------------------------------------------------
__global__ __launch_bounds__(256) void k_quant(const float* __restrict__ protos,
                                               const int* __restrict__ idx,
                                               float* __restrict__ out,
                                               float* __restrict__ vq_acc) {
    const int tid = threadIdx.x;
    const int r = blockIdx.x * 2 + (tid >> 7);
    const int c = (tid & 127) * 4;
    const int p = idx[r];
    float4 q = *(const float4*)(protos + (size_t)p * D_DIM + c);
    float4 lv = *(const float4*)(out + (size_t)r * D_DIM + c);
    float dx = q.x - lv.x, dy = q.y - lv.y, dz = q.z - lv.z, dw = q.w - lv.w;
    float s = dx * dx + dy * dy + dz * dz + dw * dw;
    *(float4*)(out + (size_t)r * D_DIM + c) = q;
#pragma unroll
    for (int m = 1; m < 64; m <<= 1) s += __shfl_xor(s, m);
    __shared__ float red[4];
    if ((tid & 63) == 0) red[tid >> 6] = s;
    __syncthreads();
    if (tid == 0) atomicAdd(vq_acc, red[0] + red[1] + red[2] + red[3]);
}

// ---------------------------------------------------------------------------
// K6: finalize scalars.
// ---------------------------------------------------------------------------
__global__ __launch_bounds__(256) void k_final(const float* __restrict__ soft_acc,
                                               const float* __restrict__ scal,
                                               float* __restrict__ out) {
    const int tid = threadIdx.x;
    __shared__ float red[256];
    float vals[8];
    float s = 0.f;
#pragma unroll
    for (int i = 0; i < 8; ++i) {
        float v = soft_acc[tid * 8 + i] * (1.0f / B_N) + 1e-6f;
        vals[i] = v;
        s += v;
    }
    red[tid] = s;
    __syncthreads();
    for (int off = 128; off > 0; off >>= 1) {
        if (tid < off) red[tid] += red[tid + off];
        __syncthreads();
    }
    float norm = red[0];
    __syncthreads();
    float e = 0.f;
#pragma unroll
    for (int i = 0; i < 8; ++i) {
        float p = vals[i] / norm;
        e -= p * __logf(p);
    }
    red[tid] = e;
    __syncthreads();
    for (int off = 128; off > 0; off >>= 1) {
        if (tid < off) red[tid] += red[tid + off];
        __syncthreads();
    }
    if (tid == 0) {
        float ent = red[0];
        float div = scal[0] * (1.0f / B_N);
        float vq = scal[1] * (1.0f / ((float)B_N * (float)D_DIM));
        float vq_loss = 1.25f * vq + 0.1f * ent;
        float total = 0.01f * div + vq_loss;
        out[(size_t)B_N * D_DIM] = total;
        out[(size_t)B_N * D_DIM + 1] = div;
    }
}

// ---------------------------------------------------------------------------
extern "C" void kernel_launch(void* const* d_in, const int* in_sizes, int n_in,
                              void* d_out, int out_size, void* d_ws, size_t ws_size,
                              hipStream_t stream) {
    const float* x = (const float*)d_in[0];
    const float* W0 = (const float*)d_in[1];
    const float* b0 = (const float*)d_in[2];
    const float* W1 = (const float*)d_in[3];
    const float* b1 = (const float*)d_in[4];
    const float* Wmu = (const float*)d_in[5];
    const float* bmu = (const float*)d_in[6];
    const float* Wvar = (const float*)d_in[7];
    const float* bvar = (const float*)d_in[8];
    const float* protos = (const float*)d_in[9];
    const float* eps = (const float*)d_in[10];
    float* out = (float*)d_out;

    unsigned short* ws = (unsigned short*)d_ws;
    unsigned short* h1b = ws;                                   // B*64 bf16
    unsigned short* h2b = h1b + (size_t)B_N * HID;              // B*512 bf16
    unsigned short* ppack = h2b + (size_t)B_N * D_DIM;          // 2048*512 bf16
    unsigned short* wmpack = ppack + (size_t)P_N * D_DIM;       // 512*512 bf16
    unsigned short* wvpack = wmpack + (size_t)D_DIM * D_DIM;    // 512*512 bf16
    unsigned short* w0pack = wvpack + (size_t)D_DIM * D_DIM;    // 64*1024 bf16
    unsigned short* w1pack = w0pack + (size_t)HID * IN_DIM;     // 512*64 bf16
    float* pnorm = (float*)(w1pack + (size_t)D_DIM * HID);      // 2048 f32
    float* soft = pnorm + P_N;                                  // 2048 f32
    float* scal = soft + P_N;                                   // 2
    int* idx = (int*)(scal + 2);                                // B int

    hipMemsetAsync(soft, 0, (P_N + 2) * sizeof(float), stream);

    k_pack<<<(HID * (IN_DIM / 8) + 255) / 256, 256, 0, stream>>>(W0, w0pack, HID, IN_DIM / 8);
    k_pack<<<(D_DIM * (HID / 8) + 255) / 256, 256, 0, stream>>>(W1, w1pack, D_DIM, HID / 8);
    k_pack<<<(P_N * (D_DIM / 8) + 255) / 256, 256, 0, stream>>>(protos, ppack, P_N, D_DIM / 8);
    k_pack<<<(D_DIM * (D_DIM / 8) + 255) / 256, 256, 0, stream>>>(Wmu, wmpack, D_DIM, D_DIM / 8);
    k_pack<<<(D_DIM * (D_DIM / 8) + 255) / 256, 256, 0, stream>>>(Wvar, wvpack, D_DIM, D_DIM / 8);
    k_pnorm<<<P_N / 4, 256, 0, stream>>>(protos, pnorm);

    k_enc1<<<B_N / 128, 256, 0, stream>>>(x, w0pack, b0, h1b);
    k_enc2<<<B_N / 64, 256, 0, stream>>>(h1b, w1pack, b1, h2b);

    const size_t smem_mv = 131072 + 8 * sizeof(float);
    k_muvar<<<B_N / 128, 512, smem_mv, stream>>>(h2b, wmpack, wvpack, bmu, bvar, eps, out, scal);

    const size_t smem_vq = 131072 + 1536;
    k_vq<<<B_N / 128, 512, smem_vq, stream>>>(out, ppack, pnorm, idx, soft);

    k_quant<<<B_N / 2, 256, 0, stream>>>(protos, idx, out, scal + 1);
    k_final<<<1, 256, 0, stream>>>(soft, scal, out);
}

// Round 6
// 639.079 us; speedup vs baseline: 2.1066x; 2.1066x over previous
//
#include <hip/hip_runtime.h>
#include <math.h>

#define B_N 32768
#define IN_DIM 1024
#define HID 64
#define D_DIM 512
#define P_N 2048

typedef __attribute__((ext_vector_type(8))) short s16x8;
typedef __attribute__((ext_vector_type(4))) float f32x4;

__device__ __forceinline__ unsigned short f2bf(float f) {
    unsigned u = __float_as_uint(f);
    return (unsigned short)((u + 0x7fffu + ((u >> 16) & 1u)) >> 16);
}

// async global->LDS, 16B per lane; lds dest = wave-uniform base + lane*16
__device__ __forceinline__ void gl_lds(const void* gsrc, void* ldst) {
    __builtin_amdgcn_global_load_lds(
        (const __attribute__((address_space(1))) unsigned int*)gsrc,
        (__attribute__((address_space(3))) unsigned int*)ldst, 16, 0, 0);
}

// ---------------------------------------------------------------------------
// Pack fp32 [nrows, ncols] row-major -> bf16 MFMA-B-fragment-major (enc1/enc2)
// ---------------------------------------------------------------------------
__global__ __launch_bounds__(256) void k_pack(const float* __restrict__ src,
                                              unsigned short* __restrict__ dst,
                                              int nrows, int nk8) {
    int gid = blockIdx.x * 256 + threadIdx.x;
    if (gid >= nrows * nk8) return;
    int row = gid / nk8, k8 = gid % nk8;
    int K32 = k8 >> 2;
    int lane = (row & 15) | ((k8 & 3) << 4);
    int P16 = row >> 4;
    int nk32 = nk8 >> 2;
    const float* s = src + (size_t)row * (nk8 * 8) + k8 * 8;
    float4 x = *(const float4*)s;
    float4 y = *(const float4*)(s + 4);
    s16x8 o;
    o[0] = (short)f2bf(x.x); o[1] = (short)f2bf(x.y);
    o[2] = (short)f2bf(x.z); o[3] = (short)f2bf(x.w);
    o[4] = (short)f2bf(y.x); o[5] = (short)f2bf(y.y);
    o[6] = (short)f2bf(y.z); o[7] = (short)f2bf(y.w);
    ((s16x8*)dst)[((size_t)P16 * nk32 + K32) * 64 + lane] = o;
}

// ---------------------------------------------------------------------------
// Pack fp32 row-major -> bf16 row-major (protos -> pb16). nrows x 512.
// ---------------------------------------------------------------------------
__global__ __launch_bounds__(256) void k_packrm(const float* __restrict__ src,
                                                unsigned short* __restrict__ dst,
                                                int nrows) {
    int gid = blockIdx.x * 256 + threadIdx.x;
    if (gid >= nrows * 64) return;
    int row = gid >> 6, k8 = gid & 63;
    const float* s = src + (size_t)row * 512 + k8 * 8;
    float4 x = *(const float4*)s;
    float4 y = *(const float4*)(s + 4);
    s16x8 o;
    o[0] = (short)f2bf(x.x); o[1] = (short)f2bf(x.y);
    o[2] = (short)f2bf(x.z); o[3] = (short)f2bf(x.w);
    o[4] = (short)f2bf(y.x); o[5] = (short)f2bf(y.y);
    o[6] = (short)f2bf(y.z); o[7] = (short)f2bf(y.w);
    ((s16x8*)(dst))[(size_t)row * 64 + k8] = o;
}

// ---------------------------------------------------------------------------
// Pack Wmu/Wvar -> row-interleaved bf16 [1024][512]: row 2d=Wmu[d], 2d+1=Wvar[d]
// ---------------------------------------------------------------------------
__global__ __launch_bounds__(256) void k_packmv(const float* __restrict__ Wmu,
                                                const float* __restrict__ Wvar,
                                                unsigned short* __restrict__ dst) {
    int gid = blockIdx.x * 256 + threadIdx.x;   // 1024*64
    int row = gid >> 6, k8 = gid & 63;
    const float* s = ((row & 1) ? Wvar : Wmu) + (size_t)(row >> 1) * 512 + k8 * 8;
    float4 x = *(const float4*)s;
    float4 y = *(const float4*)(s + 4);
    s16x8 o;
    o[0] = (short)f2bf(x.x); o[1] = (short)f2bf(x.y);
    o[2] = (short)f2bf(x.z); o[3] = (short)f2bf(x.w);
    o[4] = (short)f2bf(y.x); o[5] = (short)f2bf(y.y);
    o[6] = (short)f2bf(y.z); o[7] = (short)f2bf(y.w);
    ((s16x8*)(dst))[(size_t)row * 64 + k8] = o;
}

// ---------------------------------------------------------------------------
// K1 (MFMA): h1 = relu(x @ W0^T + b0)  [B,1024] -> [B,64] bf16 out
// ---------------------------------------------------------------------------
__global__ __launch_bounds__(256, 4) void k_enc1(const float* __restrict__ x,
                                                 const unsigned short* __restrict__ w0p,
                                                 const float* __restrict__ b0,
                                                 unsigned short* __restrict__ h1b) {
    __shared__ s16x8 As[2048];  // 128 rows x 128 bf16, 32 KB
    const int tid = threadIdx.x;
    const int l = tid & 63, wid = tid >> 6;
    const int bm = blockIdx.x * 128;
    const s16x8* w0p8 = (const s16x8*)w0p;

    const int srow = tid >> 1, ssub = tid & 1;
    const int srb = srow * 256, ssw = (srow & 7) << 4;

    const int klane = (l >> 4) << 4;
    const int sw = (l & 7) << 4;
    int aoff[2];
#pragma unroll
    for (int m = 0; m < 2; ++m) aoff[m] = (wid * 32 + m * 16 + (l & 15)) * 256;

    f32x4 acc[2][4];
#pragma unroll
    for (int m = 0; m < 2; ++m)
#pragma unroll
        for (int pf = 0; pf < 4; ++pf) acc[m][pf] = (f32x4)0.f;

    for (int kt = 0; kt < 8; ++kt) {
        const float* src = x + (size_t)(bm + srow) * IN_DIM + kt * 128 + ssub * 64;
#pragma unroll
        for (int it = 0; it < 8; ++it) {
            float4 a = *(const float4*)(src + it * 8);
            float4 b = *(const float4*)(src + it * 8 + 4);
            s16x8 o;
            o[0] = (short)f2bf(a.x); o[1] = (short)f2bf(a.y);
            o[2] = (short)f2bf(a.z); o[3] = (short)f2bf(a.w);
            o[4] = (short)f2bf(b.x); o[5] = (short)f2bf(b.y);
            o[6] = (short)f2bf(b.z); o[7] = (short)f2bf(b.w);
            int kbyte = ssub * 128 + it * 16;
            As[(srb + (kbyte ^ ssw)) >> 4] = o;
        }
        __syncthreads();
#pragma unroll
        for (int K32 = 0; K32 < 4; ++K32) {
            const int Kg = kt * 4 + K32;
            s16x8 b[4];
#pragma unroll
            for (int pf = 0; pf < 4; ++pf) b[pf] = w0p8[((size_t)pf * 32 + Kg) * 64 + l];
            const int kb = (K32 * 64 + klane) ^ sw;
            s16x8 a[2];
#pragma unroll
            for (int m = 0; m < 2; ++m) a[m] = As[(aoff[m] + kb) >> 4];
#pragma unroll
            for (int m = 0; m < 2; ++m)
#pragma unroll
                for (int pf = 0; pf < 4; ++pf)
                    acc[m][pf] = __builtin_amdgcn_mfma_f32_16x16x32_bf16(a[m], b[pf], acc[m][pf], 0, 0, 0);
        }
        __syncthreads();
    }
#pragma unroll
    for (int m = 0; m < 2; ++m)
#pragma unroll
        for (int pf = 0; pf < 4; ++pf) {
            const int c = pf * 16 + (l & 15);
            const float bb = b0[c];
#pragma unroll
            for (int j = 0; j < 4; ++j) {
                const int r = bm + wid * 32 + m * 16 + (l >> 4) * 4 + j;
                h1b[(size_t)r * HID + c] = f2bf(fmaxf(acc[m][pf][j] + bb, 0.f));
            }
        }
}

// ---------------------------------------------------------------------------
// K2 (MFMA): h2 = relu(h1 @ W1^T + b1)  [B,64] -> [B,512] bf16
// ---------------------------------------------------------------------------
__global__ __launch_bounds__(256, 4) void k_enc2(const unsigned short* __restrict__ h1b,
                                                 const unsigned short* __restrict__ w1p,
                                                 const float* __restrict__ b1,
                                                 unsigned short* __restrict__ h2b) {
    __shared__ s16x8 As[512];  // 64 rows x 64 bf16, 8 KB
    const int tid = threadIdx.x;
    const int l = tid & 63, wid = tid >> 6;
    const int bm = blockIdx.x * 64;
    const s16x8* w1p8 = (const s16x8*)w1p;

#pragma unroll
    for (int it = 0; it < 2; ++it) {
        int g = tid * 2 + it;
        int row = g >> 3, k8 = g & 7;
        s16x8 v = ((const s16x8*)(h1b + (size_t)(bm + row) * HID))[k8];
        As[(row * 128 + ((k8 * 16) ^ ((row & 7) << 4))) >> 4] = v;
    }
    __syncthreads();

    const int arow = wid * 16 + (l & 15);
    const int sw = (l & 7) << 4;
    const int klane = (l >> 4) << 4;
    s16x8 a[2];
#pragma unroll
    for (int K32 = 0; K32 < 2; ++K32)
        a[K32] = As[(arow * 128 + ((K32 * 64 + klane) ^ sw)) >> 4];

    const int r0 = bm + wid * 16 + (l >> 4) * 4;
#pragma unroll
    for (int ct = 0; ct < 4; ++ct) {
        f32x4 acc[8];
#pragma unroll
        for (int pf = 0; pf < 8; ++pf) acc[pf] = (f32x4)0.f;
#pragma unroll
        for (int K32 = 0; K32 < 2; ++K32)
#pragma unroll
            for (int pf = 0; pf < 8; ++pf) {
                s16x8 b = w1p8[(((size_t)(ct * 8 + pf)) * 2 + K32) * 64 + l];
                acc[pf] = __builtin_amdgcn_mfma_f32_16x16x32_bf16(a[K32], b, acc[pf], 0, 0, 0);
            }
#pragma unroll
        for (int pf = 0; pf < 8; ++pf) {
            const int c = ct * 128 + pf * 16 + (l & 15);
            const float bb = b1[c];
#pragma unroll
            for (int j = 0; j < 4; ++j)
                h2b[(size_t)(r0 + j) * D_DIM + c] = f2bf(fmaxf(acc[pf][j] + bb, 0.f));
        }
    }
}

// ===========================================================================
// m97-style GEMM core: BM=BN=128, BK=64, 256 thr / 4 waves, 32 KB LDS,
// global_load_lds staging for A and B (both row-major bf16, K-stride 512).
// Wave (wr,wc) owns the 64x64 quadrant; acc[m][n] 4x4 fp32x4 frags.
// ===========================================================================
#define GEMM_CORE(Aptr, Bptr)                                                  \
    __shared__ s16x8 A8[1024];                                                 \
    __shared__ s16x8 B8[1024];                                                 \
    const int tid = threadIdx.x;                                               \
    const int l = tid & 63, w = tid >> 6;                                      \
    const int bm = blockIdx.x * 128;                                           \
    const int bn = blockIdx.y * 128;                                           \
    const int wr = w >> 1, wc = w & 1;                                         \
    const int srow = l >> 3;                                                   \
    const int scol = (l & 7) * 8;                                              \
    f32x4 acc[4][4];                                                           \
    _Pragma("unroll") for (int m = 0; m < 4; ++m)                              \
        _Pragma("unroll") for (int n = 0; n < 4; ++n) acc[m][n] = (f32x4)0.f;  \
    for (int kt = 0; kt < 8; ++kt) {                                           \
        __syncthreads();                                                       \
        _Pragma("unroll") for (int i = 0; i < 4; ++i) {                        \
            const int rb = w * 32 + i * 8;                                     \
            gl_lds(Aptr + (size_t)(bm + rb + srow) * 512 + kt * 64 + scol,     \
                   (char*)A8 + rb * 128);                                      \
            gl_lds(Bptr + (size_t)(bn + rb + srow) * 512 + kt * 64 + scol,     \
                   (char*)B8 + rb * 128);                                      \
        }                                                                      \
        __syncthreads();                                                       \
        _Pragma("unroll") for (int K32 = 0; K32 < 2; ++K32) {                  \
            const int kb = K32 * 64 + (l >> 4) * 16;                           \
            s16x8 a[4], b[4];                                                  \
            _Pragma("unroll") for (int m = 0; m < 4; ++m)                      \
                a[m] = A8[((wr * 64 + m * 16 + (l & 15)) * 128 + kb) >> 4];    \
            _Pragma("unroll") for (int n = 0; n < 4; ++n)                      \
                b[n] = B8[((wc * 64 + n * 16 + (l & 15)) * 128 + kb) >> 4];    \
            _Pragma("unroll") for (int m = 0; m < 4; ++m)                      \
                _Pragma("unroll") for (int n = 0; n < 4; ++n)                  \
                    acc[m][n] = __builtin_amdgcn_mfma_f32_16x16x32_bf16(       \
                        a[m], b[n], acc[m][n], 0, 0, 0);                       \
        }                                                                      \
    }

// ---------------------------------------------------------------------------
// K3 (GEMM): mu/var (interleaved cols) + reparameterize + KL.
// grid (256, 8). Even global col = mu(d=col/2), odd = var. shfl_xor(1) pairs.
// ---------------------------------------------------------------------------
__global__ __launch_bounds__(256, 4) void k_mv(const unsigned short* __restrict__ h2b,
                                               const unsigned short* __restrict__ wmv16,
                                               const float* __restrict__ bmu,
                                               const float* __restrict__ bvar,
                                               const float* __restrict__ eps,
                                               float* __restrict__ lat32,
                                               unsigned short* __restrict__ lat16,
                                               float* __restrict__ div_acc) {
    GEMM_CORE(h2b, wmv16)
    __shared__ float red[4];
    const int lpar = l & 1;
    float kl = 0.f;
#pragma unroll
    for (int m = 0; m < 4; ++m)
#pragma unroll
        for (int n = 0; n < 4; ++n) {
            const int col = bn + wc * 64 + n * 16 + (l & 15);
            const int d = col >> 1;
            const float bias = lpar ? bvar[d] : bmu[d];
#pragma unroll
            for (int j = 0; j < 4; ++j) {
                const int row = bm + wr * 64 + m * 16 + (l >> 4) * 4 + j;
                float val = acc[m][n][j] + bias;
                float other = __shfl_xor(val, 1);
                if (lpar == 0) {
                    float la = fmaf(eps[(size_t)row * D_DIM + d], __expf(0.5f * other), val);
                    lat32[(size_t)row * D_DIM + d] = la;
                    lat16[(size_t)row * D_DIM + d] = f2bf(la);
                    kl += val * val;
                } else {
                    kl += __expf(val) - val - 1.f;
                }
            }
        }
    kl *= 0.5f;
#pragma unroll
    for (int d = 1; d < 64; d <<= 1) kl += __shfl_xor(kl, d);
    if (l == 0) red[w] = kl;
    __syncthreads();
    if (tid == 0) atomicAdd(div_acc, red[0] + red[1] + red[2] + red[3]);
}

// ---------------------------------------------------------------------------
// K4a: pnorm[p] = sum_d protos[p,d]^2
// ---------------------------------------------------------------------------
__global__ __launch_bounds__(256) void k_pnorm(const float* __restrict__ protos,
                                               float* __restrict__ pnorm) {
    const int p = blockIdx.x * 4 + (threadIdx.x >> 6);
    const int lane = threadIdx.x & 63;
    const float* row = protos + (size_t)p * D_DIM;
    float4 v1 = *(const float4*)(row + lane * 8);
    float4 v2 = *(const float4*)(row + lane * 8 + 4);
    float s = v1.x * v1.x + v1.y * v1.y + v1.z * v1.z + v1.w * v1.w +
              v2.x * v2.x + v2.y * v2.y + v2.z * v2.z + v2.w * v2.w;
#pragma unroll
    for (int m = 1; m < 64; m <<= 1) s += __shfl_xor(s, m);
    if (lane == 0) pnorm[p] = s;
}

// ---------------------------------------------------------------------------
// K4 (GEMM sweep0): g = 2*latents.protos - |p|^2; per-row sumexp + packed-key
// argmax merged across blocks via global atomics. grid (256, 16).
// key = (bits(g+16) & ~0x7FF) | (2047-p): monotone in g (quantum ~0.004),
// tie -> smaller p.
// ---------------------------------------------------------------------------
__global__ __launch_bounds__(256, 4) void k_vq1(const unsigned short* __restrict__ lat16,
                                                const unsigned short* __restrict__ pb16,
                                                const float* __restrict__ pnorm,
                                                float* __restrict__ rowS,
                                                unsigned* __restrict__ rowKey) {
    GEMM_CORE(lat16, pb16)
    float pn[4];
#pragma unroll
    for (int n = 0; n < 4; ++n) pn[n] = pnorm[bn + wc * 64 + n * 16 + (l & 15)];
#pragma unroll
    for (int m = 0; m < 4; ++m)
#pragma unroll
        for (int j = 0; j < 4; ++j) {
            float se = 0.f;
            unsigned key = 0u;
#pragma unroll
            for (int n = 0; n < 4; ++n) {
                const int p = bn + wc * 64 + n * 16 + (l & 15);
                float g = 2.f * acc[m][n][j] - pn[n];
                se += __expf(g);
                unsigned kk = (__float_as_uint(g + 16.0f) & 0xFFFFF800u) | (unsigned)(2047 - p);
                key = key > kk ? key : kk;
            }
#pragma unroll
            for (int d = 1; d < 16; d <<= 1) {
                se += __shfl_xor(se, d);
                unsigned ok = (unsigned)__shfl_xor((int)key, d);
                key = key > ok ? key : ok;
            }
            if ((l & 15) == 0) {
                const int row = bm + wr * 64 + m * 16 + (l >> 4) * 4 + j;
                atomicAdd(&rowS[row], se);
                atomicMax(&rowKey[row], key);
            }
        }
}

// ---------------------------------------------------------------------------
// K5 (GEMM sweep1): soft_acc[p] += sum_rows exp(g)/rowS[row]. grid (256, 16).
// ---------------------------------------------------------------------------
__global__ __launch_bounds__(256, 4) void k_vq2(const unsigned short* __restrict__ lat16,
                                                const unsigned short* __restrict__ pb16,
                                                const float* __restrict__ pnorm,
                                                const float* __restrict__ rowS,
                                                float* __restrict__ soft_acc) {
    __shared__ float soft_l[128];
    if (threadIdx.x < 128) soft_l[threadIdx.x] = 0.f;
    GEMM_CORE(lat16, pb16)
    float pn[4];
#pragma unroll
    for (int n = 0; n < 4; ++n) pn[n] = pnorm[bn + wc * 64 + n * 16 + (l & 15)];
    float cs[4] = {0.f, 0.f, 0.f, 0.f};
#pragma unroll
    for (int m = 0; m < 4; ++m)
#pragma unroll
        for (int j = 0; j < 4; ++j) {
            const int row = bm + wr * 64 + m * 16 + (l >> 4) * 4 + j;
            const float is = 1.0f / rowS[row];
#pragma unroll
            for (int n = 0; n < 4; ++n) {
                float g = 2.f * acc[m][n][j] - pn[n];
                cs[n] += __expf(g) * is;
            }
        }
#pragma unroll
    for (int n = 0; n < 4; ++n) {
        cs[n] += __shfl_xor(cs[n], 16);
        cs[n] += __shfl_xor(cs[n], 32);
    }
    if (l < 16) {
#pragma unroll
        for (int n = 0; n < 4; ++n) atomicAdd(&soft_l[wc * 64 + n * 16 + l], cs[n]);
    }
    __syncthreads();
    if (tid < 128) atomicAdd(&soft_acc[bn + tid], soft_l[tid]);
}

// ---------------------------------------------------------------------------
// K6: out[r,:] = protos[idx[r],:] (idx from rowKey) + vq partial sums
// ---------------------------------------------------------------------------
__global__ __launch_bounds__(256) void k_quant(const float* __restrict__ protos,
                                               const unsigned* __restrict__ rowKey,
                                               float* __restrict__ out,
                                               float* __restrict__ vq_acc) {
    const int tid = threadIdx.x;
    const int r = blockIdx.x * 2 + (tid >> 7);
    const int c = (tid & 127) * 4;
    const int p = 2047 - (int)(rowKey[r] & 2047u);
    float4 q = *(const float4*)(protos + (size_t)p * D_DIM + c);
    float4 lv = *(const float4*)(out + (size_t)r * D_DIM + c);
    float dx = q.x - lv.x, dy = q.y - lv.y, dz = q.z - lv.z, dw = q.w - lv.w;
    float s = dx * dx + dy * dy + dz * dz + dw * dw;
    *(float4*)(out + (size_t)r * D_DIM + c) = q;
#pragma unroll
    for (int m = 1; m < 64; m <<= 1) s += __shfl_xor(s, m);
    __shared__ float red[4];
    if ((tid & 63) == 0) red[tid >> 6] = s;
    __syncthreads();
    if (tid == 0) atomicAdd(vq_acc, red[0] + red[1] + red[2] + red[3]);
}

// ---------------------------------------------------------------------------
// K7: finalize scalars.
// ---------------------------------------------------------------------------
__global__ __launch_bounds__(256) void k_final(const float* __restrict__ soft_acc,
                                               const float* __restrict__ scal,
                                               float* __restrict__ out) {
    const int tid = threadIdx.x;
    __shared__ float red[256];
    float vals[8];
    float s = 0.f;
#pragma unroll
    for (int i = 0; i < 8; ++i) {
        float v = soft_acc[tid * 8 + i] * (1.0f / B_N) + 1e-6f;
        vals[i] = v;
        s += v;
    }
    red[tid] = s;
    __syncthreads();
    for (int off = 128; off > 0; off >>= 1) {
        if (tid < off) red[tid] += red[tid + off];
        __syncthreads();
    }
    float norm = red[0];
    __syncthreads();
    float e = 0.f;
#pragma unroll
    for (int i = 0; i < 8; ++i) {
        float p = vals[i] / norm;
        e -= p * __logf(p);
    }
    red[tid] = e;
    __syncthreads();
    for (int off = 128; off > 0; off >>= 1) {
        if (tid < off) red[tid] += red[tid + off];
        __syncthreads();
    }
    if (tid == 0) {
        float ent = red[0];
        float div = scal[0] * (1.0f / B_N);
        float vq = scal[1] * (1.0f / ((float)B_N * (float)D_DIM));
        float vq_loss = 1.25f * vq + 0.1f * ent;
        float total = 0.01f * div + vq_loss;
        out[(size_t)B_N * D_DIM] = total;
        out[(size_t)B_N * D_DIM + 1] = div;
    }
}

// ---------------------------------------------------------------------------
extern "C" void kernel_launch(void* const* d_in, const int* in_sizes, int n_in,
                              void* d_out, int out_size, void* d_ws, size_t ws_size,
                              hipStream_t stream) {
    const float* x = (const float*)d_in[0];
    const float* W0 = (const float*)d_in[1];
    const float* b0 = (const float*)d_in[2];
    const float* W1 = (const float*)d_in[3];
    const float* b1 = (const float*)d_in[4];
    const float* Wmu = (const float*)d_in[5];
    const float* bmu = (const float*)d_in[6];
    const float* Wvar = (const float*)d_in[7];
    const float* bvar = (const float*)d_in[8];
    const float* protos = (const float*)d_in[9];
    const float* eps = (const float*)d_in[10];
    float* out = (float*)d_out;

    unsigned short* wsp = (unsigned short*)d_ws;
    unsigned short* h1b = wsp;                                  // B*64 bf16
    unsigned short* h2b = h1b + (size_t)B_N * HID;              // B*512
    unsigned short* lat16 = h2b + (size_t)B_N * D_DIM;          // B*512
    unsigned short* pb16 = lat16 + (size_t)B_N * D_DIM;         // 2048*512
    unsigned short* wmv16 = pb16 + (size_t)P_N * D_DIM;         // 1024*512
    unsigned short* w0pack = wmv16 + (size_t)2 * D_DIM * D_DIM; // 64*1024
    unsigned short* w1pack = w0pack + (size_t)HID * IN_DIM;     // 512*64
    float* pnorm = (float*)(w1pack + (size_t)D_DIM * HID);      // 2048
    float* rowS = pnorm + P_N;                                  // 32768
    unsigned* rowKey = (unsigned*)(rowS + B_N);                 // 32768
    float* soft = (float*)(rowKey + B_N);                       // 2048
    float* scal = soft + P_N;                                   // 2

    // zero rowS, rowKey, soft, scal (contiguous)
    hipMemsetAsync(rowS, 0, (size_t)(B_N * 2 + P_N + 2) * 4, stream);

    k_pack<<<(HID * (IN_DIM / 8) + 255) / 256, 256, 0, stream>>>(W0, w0pack, HID, IN_DIM / 8);
    k_pack<<<(D_DIM * (HID / 8) + 255) / 256, 256, 0, stream>>>(W1, w1pack, D_DIM, HID / 8);
    k_packrm<<<P_N * 64 / 256, 256, 0, stream>>>(protos, pb16, P_N);
    k_packmv<<<1024 * 64 / 256, 256, 0, stream>>>(Wmu, Wvar, wmv16);
    k_pnorm<<<P_N / 4, 256, 0, stream>>>(protos, pnorm);

    k_enc1<<<B_N / 128, 256, 0, stream>>>(x, w0pack, b0, h1b);
    k_enc2<<<B_N / 64, 256, 0, stream>>>(h1b, w1pack, b1, h2b);

    dim3 gmv(B_N / 128, 8);
    k_mv<<<gmv, 256, 0, stream>>>(h2b, wmv16, bmu, bvar, eps, out, lat16, scal);

    dim3 gvq(B_N / 128, 16);
    k_vq1<<<gvq, 256, 0, stream>>>(lat16, pb16, pnorm, rowS, rowKey);
    k_vq2<<<gvq, 256, 0, stream>>>(lat16, pb16, pnorm, rowS, soft);

    k_quant<<<B_N / 2, 256, 0, stream>>>(protos, rowKey, out, scal + 1);
    k_final<<<1, 256, 0, stream>>>(soft, scal, out);
}

// Round 7
// 454.476 us; speedup vs baseline: 2.9622x; 1.4062x over previous
//
#include <hip/hip_runtime.h>
#include <math.h>

#define B_N 32768
#define IN_DIM 1024
#define HID 64
#define D_DIM 512
#define P_N 2048

typedef __attribute__((ext_vector_type(8))) short s16x8;
typedef __attribute__((ext_vector_type(4))) float f32x4;

__device__ __forceinline__ unsigned short f2bf(float f) {
    unsigned u = __float_as_uint(f);
    return (unsigned short)((u + 0x7fffu + ((u >> 16) & 1u)) >> 16);
}

// async global->LDS, 16B per lane; lds dest = wave-uniform base + lane*16
__device__ __forceinline__ void gl_lds(const void* gsrc, void* ldst) {
    __builtin_amdgcn_global_load_lds(
        (const __attribute__((address_space(1))) unsigned int*)gsrc,
        (__attribute__((address_space(3))) unsigned int*)ldst, 16, 0, 0);
}

// ---------------------------------------------------------------------------
// Pack fp32 [nrows, ncols] row-major -> bf16 MFMA-B-fragment-major (enc1/enc2)
// ---------------------------------------------------------------------------
__global__ __launch_bounds__(256) void k_pack(const float* __restrict__ src,
                                              unsigned short* __restrict__ dst,
                                              int nrows, int nk8) {
    int gid = blockIdx.x * 256 + threadIdx.x;
    if (gid >= nrows * nk8) return;
    int row = gid / nk8, k8 = gid % nk8;
    int K32 = k8 >> 2;
    int lane = (row & 15) | ((k8 & 3) << 4);
    int P16 = row >> 4;
    int nk32 = nk8 >> 2;
    const float* s = src + (size_t)row * (nk8 * 8) + k8 * 8;
    float4 x = *(const float4*)s;
    float4 y = *(const float4*)(s + 4);
    s16x8 o;
    o[0] = (short)f2bf(x.x); o[1] = (short)f2bf(x.y);
    o[2] = (short)f2bf(x.z); o[3] = (short)f2bf(x.w);
    o[4] = (short)f2bf(y.x); o[5] = (short)f2bf(y.y);
    o[6] = (short)f2bf(y.z); o[7] = (short)f2bf(y.w);
    ((s16x8*)dst)[((size_t)P16 * nk32 + K32) * 64 + lane] = o;
}

// ---------------------------------------------------------------------------
// Pack fp32 row-major -> bf16 row-major (protos -> pb16). nrows x 512.
// ---------------------------------------------------------------------------
__global__ __launch_bounds__(256) void k_packrm(const float* __restrict__ src,
                                                unsigned short* __restrict__ dst,
                                                int nrows) {
    int gid = blockIdx.x * 256 + threadIdx.x;
    if (gid >= nrows * 64) return;
    int row = gid >> 6, k8 = gid & 63;
    const float* s = src + (size_t)row * 512 + k8 * 8;
    float4 x = *(const float4*)s;
    float4 y = *(const float4*)(s + 4);
    s16x8 o;
    o[0] = (short)f2bf(x.x); o[1] = (short)f2bf(x.y);
    o[2] = (short)f2bf(x.z); o[3] = (short)f2bf(x.w);
    o[4] = (short)f2bf(y.x); o[5] = (short)f2bf(y.y);
    o[6] = (short)f2bf(y.z); o[7] = (short)f2bf(y.w);
    ((s16x8*)(dst))[(size_t)row * 64 + k8] = o;
}

// ---------------------------------------------------------------------------
// Pack Wmu/Wvar -> row-interleaved bf16 [1024][512]: row 2d=Wmu[d], 2d+1=Wvar[d]
// ---------------------------------------------------------------------------
__global__ __launch_bounds__(256) void k_packmv(const float* __restrict__ Wmu,
                                                const float* __restrict__ Wvar,
                                                unsigned short* __restrict__ dst) {
    int gid = blockIdx.x * 256 + threadIdx.x;   // 1024*64
    int row = gid >> 6, k8 = gid & 63;
    const float* s = ((row & 1) ? Wvar : Wmu) + (size_t)(row >> 1) * 512 + k8 * 8;
    float4 x = *(const float4*)s;
    float4 y = *(const float4*)(s + 4);
    s16x8 o;
    o[0] = (short)f2bf(x.x); o[1] = (short)f2bf(x.y);
    o[2] = (short)f2bf(x.z); o[3] = (short)f2bf(x.w);
    o[4] = (short)f2bf(y.x); o[5] = (short)f2bf(y.y);
    o[6] = (short)f2bf(y.z); o[7] = (short)f2bf(y.w);
    ((s16x8*)(dst))[(size_t)row * 64 + k8] = o;
}

// ---------------------------------------------------------------------------
// K1 (MFMA): h1 = relu(x @ W0^T + b0)  [B,1024] -> [B,64] bf16 out
// ---------------------------------------------------------------------------
__global__ __launch_bounds__(256, 4) void k_enc1(const float* __restrict__ x,
                                                 const unsigned short* __restrict__ w0p,
                                                 const float* __restrict__ b0,
                                                 unsigned short* __restrict__ h1b) {
    __shared__ s16x8 As[2048];  // 128 rows x 128 bf16, 32 KB
    const int tid = threadIdx.x;
    const int l = tid & 63, wid = tid >> 6;
    const int bm = blockIdx.x * 128;
    const s16x8* w0p8 = (const s16x8*)w0p;

    const int srow = tid >> 1, ssub = tid & 1;
    const int srb = srow * 256, ssw = (srow & 7) << 4;

    const int klane = (l >> 4) << 4;
    const int sw = (l & 7) << 4;
    int aoff[2];
#pragma unroll
    for (int m = 0; m < 2; ++m) aoff[m] = (wid * 32 + m * 16 + (l & 15)) * 256;

    f32x4 acc[2][4];
#pragma unroll
    for (int m = 0; m < 2; ++m)
#pragma unroll
        for (int pf = 0; pf < 4; ++pf) acc[m][pf] = (f32x4)0.f;

    for (int kt = 0; kt < 8; ++kt) {
        const float* src = x + (size_t)(bm + srow) * IN_DIM + kt * 128 + ssub * 64;
#pragma unroll
        for (int it = 0; it < 8; ++it) {
            float4 a = *(const float4*)(src + it * 8);
            float4 b = *(const float4*)(src + it * 8 + 4);
            s16x8 o;
            o[0] = (short)f2bf(a.x); o[1] = (short)f2bf(a.y);
            o[2] = (short)f2bf(a.z); o[3] = (short)f2bf(a.w);
            o[4] = (short)f2bf(b.x); o[5] = (short)f2bf(b.y);
            o[6] = (short)f2bf(b.z); o[7] = (short)f2bf(b.w);
            int kbyte = ssub * 128 + it * 16;
            As[(srb + (kbyte ^ ssw)) >> 4] = o;
        }
        __syncthreads();
#pragma unroll
        for (int K32 = 0; K32 < 4; ++K32) {
            const int Kg = kt * 4 + K32;
            s16x8 b[4];
#pragma unroll
            for (int pf = 0; pf < 4; ++pf) b[pf] = w0p8[((size_t)pf * 32 + Kg) * 64 + l];
            const int kb = (K32 * 64 + klane) ^ sw;
            s16x8 a[2];
#pragma unroll
            for (int m = 0; m < 2; ++m) a[m] = As[(aoff[m] + kb) >> 4];
#pragma unroll
            for (int m = 0; m < 2; ++m)
#pragma unroll
                for (int pf = 0; pf < 4; ++pf)
                    acc[m][pf] = __builtin_amdgcn_mfma_f32_16x16x32_bf16(a[m], b[pf], acc[m][pf], 0, 0, 0);
        }
        __syncthreads();
    }
#pragma unroll
    for (int m = 0; m < 2; ++m)
#pragma unroll
        for (int pf = 0; pf < 4; ++pf) {
            const int c = pf * 16 + (l & 15);
            const float bb = b0[c];
#pragma unroll
            for (int j = 0; j < 4; ++j) {
                const int r = bm + wid * 32 + m * 16 + (l >> 4) * 4 + j;
                h1b[(size_t)r * HID + c] = f2bf(fmaxf(acc[m][pf][j] + bb, 0.f));
            }
        }
}

// ---------------------------------------------------------------------------
// K2 (MFMA): h2 = relu(h1 @ W1^T + b1)  [B,64] -> [B,512] bf16
// ---------------------------------------------------------------------------
__global__ __launch_bounds__(256, 4) void k_enc2(const unsigned short* __restrict__ h1b,
                                                 const unsigned short* __restrict__ w1p,
                                                 const float* __restrict__ b1,
                                                 unsigned short* __restrict__ h2b) {
    __shared__ s16x8 As[512];  // 64 rows x 64 bf16, 8 KB
    const int tid = threadIdx.x;
    const int l = tid & 63, wid = tid >> 6;
    const int bm = blockIdx.x * 64;
    const s16x8* w1p8 = (const s16x8*)w1p;

#pragma unroll
    for (int it = 0; it < 2; ++it) {
        int g = tid * 2 + it;
        int row = g >> 3, k8 = g & 7;
        s16x8 v = ((const s16x8*)(h1b + (size_t)(bm + row) * HID))[k8];
        As[(row * 128 + ((k8 * 16) ^ ((row & 7) << 4))) >> 4] = v;
    }
    __syncthreads();

    const int arow = wid * 16 + (l & 15);
    const int sw = (l & 7) << 4;
    const int klane = (l >> 4) << 4;
    s16x8 a[2];
#pragma unroll
    for (int K32 = 0; K32 < 2; ++K32)
        a[K32] = As[(arow * 128 + ((K32 * 64 + klane) ^ sw)) >> 4];

    const int r0 = bm + wid * 16 + (l >> 4) * 4;
#pragma unroll
    for (int ct = 0; ct < 4; ++ct) {
        f32x4 acc[8];
#pragma unroll
        for (int pf = 0; pf < 8; ++pf) acc[pf] = (f32x4)0.f;
#pragma unroll
        for (int K32 = 0; K32 < 2; ++K32)
#pragma unroll
            for (int pf = 0; pf < 8; ++pf) {
                s16x8 b = w1p8[(((size_t)(ct * 8 + pf)) * 2 + K32) * 64 + l];
                acc[pf] = __builtin_amdgcn_mfma_f32_16x16x32_bf16(a[K32], b, acc[pf], 0, 0, 0);
            }
#pragma unroll
        for (int pf = 0; pf < 8; ++pf) {
            const int c = ct * 128 + pf * 16 + (l & 15);
            const float bb = b1[c];
#pragma unroll
            for (int j = 0; j < 4; ++j)
                h2b[(size_t)(r0 + j) * D_DIM + c] = f2bf(fmaxf(acc[pf][j] + bb, 0.f));
        }
    }
}

// ===========================================================================
// m97-style GEMM core: BM=BN=128, BK=64, 256 thr / 4 waves, 32 KB LDS,
// global_load_lds staging for A and B (both row-major bf16, K-stride 512).
// ===========================================================================
#define GEMM_CORE(Aptr, Bptr)                                                  \
    __shared__ s16x8 A8[1024];                                                 \
    __shared__ s16x8 B8[1024];                                                 \
    const int tid = threadIdx.x;                                               \
    const int l = tid & 63, w = tid >> 6;                                      \
    const int bm = blockIdx.x * 128;                                           \
    const int bn = blockIdx.y * 128;                                           \
    const int wr = w >> 1, wc = w & 1;                                         \
    const int srow = l >> 3;                                                   \
    const int scol = (l & 7) * 8;                                              \
    f32x4 acc[4][4];                                                           \
    _Pragma("unroll") for (int m = 0; m < 4; ++m)                              \
        _Pragma("unroll") for (int n = 0; n < 4; ++n) acc[m][n] = (f32x4)0.f;  \
    for (int kt = 0; kt < 8; ++kt) {                                           \
        __syncthreads();                                                       \
        _Pragma("unroll") for (int i = 0; i < 4; ++i) {                        \
            const int rb = w * 32 + i * 8;                                     \
            gl_lds(Aptr + (size_t)(bm + rb + srow) * 512 + kt * 64 + scol,     \
                   (char*)A8 + rb * 128);                                      \
            gl_lds(Bptr + (size_t)(bn + rb + srow) * 512 + kt * 64 + scol,     \
                   (char*)B8 + rb * 128);                                      \
        }                                                                      \
        __syncthreads();                                                       \
        _Pragma("unroll") for (int K32 = 0; K32 < 2; ++K32) {                  \
            const int kb = K32 * 64 + (l >> 4) * 16;                           \
            s16x8 a[4], b[4];                                                  \
            _Pragma("unroll") for (int m = 0; m < 4; ++m)                      \
                a[m] = A8[((wr * 64 + m * 16 + (l & 15)) * 128 + kb) >> 4];    \
            _Pragma("unroll") for (int n = 0; n < 4; ++n)                      \
                b[n] = B8[((wc * 64 + n * 16 + (l & 15)) * 128 + kb) >> 4];    \
            _Pragma("unroll") for (int m = 0; m < 4; ++m)                      \
                _Pragma("unroll") for (int n = 0; n < 4; ++n)                  \
                    acc[m][n] = __builtin_amdgcn_mfma_f32_16x16x32_bf16(       \
                        a[m], b[n], acc[m][n], 0, 0, 0);                       \
        }                                                                      \
    }

// ---------------------------------------------------------------------------
// K3 (GEMM): mu/var (interleaved cols) + reparameterize + KL.
// ---------------------------------------------------------------------------
__global__ __launch_bounds__(256, 4) void k_mv(const unsigned short* __restrict__ h2b,
                                               const unsigned short* __restrict__ wmv16,
                                               const float* __restrict__ bmu,
                                               const float* __restrict__ bvar,
                                               const float* __restrict__ eps,
                                               float* __restrict__ lat32,
                                               unsigned short* __restrict__ lat16,
                                               float* __restrict__ div_acc) {
    GEMM_CORE(h2b, wmv16)
    __shared__ float red[4];
    const int lpar = l & 1;
    float kl = 0.f;
#pragma unroll
    for (int m = 0; m < 4; ++m)
#pragma unroll
        for (int n = 0; n < 4; ++n) {
            const int col = bn + wc * 64 + n * 16 + (l & 15);
            const int d = col >> 1;
            const float bias = lpar ? bvar[d] : bmu[d];
#pragma unroll
            for (int j = 0; j < 4; ++j) {
                const int row = bm + wr * 64 + m * 16 + (l >> 4) * 4 + j;
                float val = acc[m][n][j] + bias;
                float other = __shfl_xor(val, 1);
                if (lpar == 0) {
                    float la = fmaf(eps[(size_t)row * D_DIM + d], __expf(0.5f * other), val);
                    lat32[(size_t)row * D_DIM + d] = la;
                    lat16[(size_t)row * D_DIM + d] = f2bf(la);
                    kl += val * val;
                } else {
                    kl += __expf(val) - val - 1.f;
                }
            }
        }
    kl *= 0.5f;
#pragma unroll
    for (int d = 1; d < 64; d <<= 1) kl += __shfl_xor(kl, d);
    if (l == 0) red[w] = kl;
    __syncthreads();
    if (tid == 0) atomicAdd(div_acc, red[0] + red[1] + red[2] + red[3]);
}

// ---------------------------------------------------------------------------
// K4a: pnorm[p] = sum_d protos[p,d]^2
// ---------------------------------------------------------------------------
__global__ __launch_bounds__(256) void k_pnorm(const float* __restrict__ protos,
                                               float* __restrict__ pnorm) {
    const int p = blockIdx.x * 4 + (threadIdx.x >> 6);
    const int lane = threadIdx.x & 63;
    const float* row = protos + (size_t)p * D_DIM;
    float4 v1 = *(const float4*)(row + lane * 8);
    float4 v2 = *(const float4*)(row + lane * 8 + 4);
    float s = v1.x * v1.x + v1.y * v1.y + v1.z * v1.z + v1.w * v1.w +
              v2.x * v2.x + v2.y * v2.y + v2.z * v2.z + v2.w * v2.w;
#pragma unroll
    for (int m = 1; m < 64; m <<= 1) s += __shfl_xor(s, m);
    if (lane == 0) pnorm[p] = s;
}

// ---------------------------------------------------------------------------
// K4 (GEMM sweep0): per-row sumexp + packed-key argmax via global atomics.
// ---------------------------------------------------------------------------
__global__ __launch_bounds__(256, 4) void k_vq1(const unsigned short* __restrict__ lat16,
                                                const unsigned short* __restrict__ pb16,
                                                const float* __restrict__ pnorm,
                                                float* __restrict__ rowS,
                                                unsigned* __restrict__ rowKey) {
    GEMM_CORE(lat16, pb16)
    float pn[4];
#pragma unroll
    for (int n = 0; n < 4; ++n) pn[n] = pnorm[bn + wc * 64 + n * 16 + (l & 15)];
#pragma unroll
    for (int m = 0; m < 4; ++m)
#pragma unroll
        for (int j = 0; j < 4; ++j) {
            float se = 0.f;
            unsigned key = 0u;
#pragma unroll
            for (int n = 0; n < 4; ++n) {
                const int p = bn + wc * 64 + n * 16 + (l & 15);
                float g = 2.f * acc[m][n][j] - pn[n];
                se += __expf(g);
                unsigned kk = (__float_as_uint(g + 16.0f) & 0xFFFFF800u) | (unsigned)(2047 - p);
                key = key > kk ? key : kk;
            }
#pragma unroll
            for (int d = 1; d < 16; d <<= 1) {
                se += __shfl_xor(se, d);
                unsigned ok = (unsigned)__shfl_xor((int)key, d);
                key = key > ok ? key : ok;
            }
            if ((l & 15) == 0) {
                const int row = bm + wr * 64 + m * 16 + (l >> 4) * 4 + j;
                atomicAdd(&rowS[row], se);
                atomicMax(&rowKey[row], key);
            }
        }
}

// ---------------------------------------------------------------------------
// K5 (GEMM sweep1): soft_acc[p] += sum_rows exp(g)/rowS[row].
// ---------------------------------------------------------------------------
__global__ __launch_bounds__(256, 4) void k_vq2(const unsigned short* __restrict__ lat16,
                                                const unsigned short* __restrict__ pb16,
                                                const float* __restrict__ pnorm,
                                                const float* __restrict__ rowS,
                                                float* __restrict__ soft_acc) {
    __shared__ float soft_l[128];
    if (threadIdx.x < 128) soft_l[threadIdx.x] = 0.f;
    GEMM_CORE(lat16, pb16)
    float pn[4];
#pragma unroll
    for (int n = 0; n < 4; ++n) pn[n] = pnorm[bn + wc * 64 + n * 16 + (l & 15)];
    float cs[4] = {0.f, 0.f, 0.f, 0.f};
#pragma unroll
    for (int m = 0; m < 4; ++m)
#pragma unroll
        for (int j = 0; j < 4; ++j) {
            const int row = bm + wr * 64 + m * 16 + (l >> 4) * 4 + j;
            const float is = 1.0f / rowS[row];
#pragma unroll
            for (int n = 0; n < 4; ++n) {
                float g = 2.f * acc[m][n][j] - pn[n];
                cs[n] += __expf(g) * is;
            }
        }
#pragma unroll
    for (int n = 0; n < 4; ++n) {
        cs[n] += __shfl_xor(cs[n], 16);
        cs[n] += __shfl_xor(cs[n], 32);
    }
    if (l < 16) {
#pragma unroll
        for (int n = 0; n < 4; ++n) atomicAdd(&soft_l[wc * 64 + n * 16 + l], cs[n]);
    }
    __syncthreads();
    if (tid < 128) atomicAdd(&soft_acc[bn + tid], soft_l[tid]);
}

// ---------------------------------------------------------------------------
// K6: out[r,:] = protos[idx[r],:] + vq partial sums (NO atomics: partial array)
// grid = B/64 = 512 blocks; wave handles a row per iter (16 iters).
// ---------------------------------------------------------------------------
__global__ __launch_bounds__(256) void k_quant(const float* __restrict__ protos,
                                               const unsigned* __restrict__ rowKey,
                                               float* __restrict__ out,
                                               float* __restrict__ vq_part) {
    const int tid = threadIdx.x;
    const int l = tid & 63, wid = tid >> 6;
    const int base = blockIdx.x * 64;
    float s = 0.f;
#pragma unroll
    for (int it = 0; it < 16; ++it) {
        const int r = base + it * 4 + wid;
        const int p = 2047 - (int)(rowKey[r] & 2047u);
        const float4* qp = (const float4*)(protos + (size_t)p * D_DIM);
        float4* op = (float4*)(out + (size_t)r * D_DIM);
        float4 q1 = qp[l * 2], q2 = qp[l * 2 + 1];
        float4 l1 = op[l * 2], l2 = op[l * 2 + 1];
        float dx, dy, dz, dw;
        dx = q1.x - l1.x; dy = q1.y - l1.y; dz = q1.z - l1.z; dw = q1.w - l1.w;
        s += dx * dx + dy * dy + dz * dz + dw * dw;
        dx = q2.x - l2.x; dy = q2.y - l2.y; dz = q2.z - l2.z; dw = q2.w - l2.w;
        s += dx * dx + dy * dy + dz * dz + dw * dw;
        op[l * 2] = q1; op[l * 2 + 1] = q2;
    }
#pragma unroll
    for (int m = 1; m < 64; m <<= 1) s += __shfl_xor(s, m);
    __shared__ float red[4];
    if (l == 0) red[wid] = s;
    __syncthreads();
    if (tid == 0) vq_part[blockIdx.x] = red[0] + red[1] + red[2] + red[3];
}

// ---------------------------------------------------------------------------
// K7: finalize scalars.  vq sum from 512 partials (no atomics upstream).
// ---------------------------------------------------------------------------
__global__ __launch_bounds__(256) void k_final(const float* __restrict__ soft_acc,
                                               const float* __restrict__ scal,
                                               const float* __restrict__ vq_part,
                                               float* __restrict__ out) {
    const int tid = threadIdx.x;
    __shared__ float red[256];
    float vals[8];
    float s = 0.f;
#pragma unroll
    for (int i = 0; i < 8; ++i) {
        float v = soft_acc[tid * 8 + i] * (1.0f / B_N) + 1e-6f;
        vals[i] = v;
        s += v;
    }
    red[tid] = s;
    __syncthreads();
    for (int off = 128; off > 0; off >>= 1) {
        if (tid < off) red[tid] += red[tid + off];
        __syncthreads();
    }
    float norm = red[0];
    __syncthreads();
    float e = 0.f;
#pragma unroll
    for (int i = 0; i < 8; ++i) {
        float p = vals[i] / norm;
        e -= p * __logf(p);
    }
    red[tid] = e;
    __syncthreads();
    for (int off = 128; off > 0; off >>= 1) {
        if (tid < off) red[tid] += red[tid + off];
        __syncthreads();
    }
    float ent = red[0];
    __syncthreads();
    red[tid] = vq_part[tid] + vq_part[tid + 256];
    __syncthreads();
    for (int off = 128; off > 0; off >>= 1) {
        if (tid < off) red[tid] += red[tid + off];
        __syncthreads();
    }
    if (tid == 0) {
        float div = scal[0] * (1.0f / B_N);
        float vq = red[0] * (1.0f / ((float)B_N * (float)D_DIM));
        float vq_loss = 1.25f * vq + 0.1f * ent;
        float total = 0.01f * div + vq_loss;
        out[(size_t)B_N * D_DIM] = total;
        out[(size_t)B_N * D_DIM + 1] = div;
    }
}

// ---------------------------------------------------------------------------
extern "C" void kernel_launch(void* const* d_in, const int* in_sizes, int n_in,
                              void* d_out, int out_size, void* d_ws, size_t ws_size,
                              hipStream_t stream) {
    const float* x = (const float*)d_in[0];
    const float* W0 = (const float*)d_in[1];
    const float* b0 = (const float*)d_in[2];
    const float* W1 = (const float*)d_in[3];
    const float* b1 = (const float*)d_in[4];
    const float* Wmu = (const float*)d_in[5];
    const float* bmu = (const float*)d_in[6];
    const float* Wvar = (const float*)d_in[7];
    const float* bvar = (const float*)d_in[8];
    const float* protos = (const float*)d_in[9];
    const float* eps = (const float*)d_in[10];
    float* out = (float*)d_out;

    unsigned short* wsp = (unsigned short*)d_ws;
    unsigned short* h1b = wsp;                                  // B*64 bf16
    unsigned short* h2b = h1b + (size_t)B_N * HID;              // B*512
    unsigned short* lat16 = h2b + (size_t)B_N * D_DIM;          // B*512
    unsigned short* pb16 = lat16 + (size_t)B_N * D_DIM;         // 2048*512
    unsigned short* wmv16 = pb16 + (size_t)P_N * D_DIM;         // 1024*512
    unsigned short* w0pack = wmv16 + (size_t)2 * D_DIM * D_DIM; // 64*1024
    unsigned short* w1pack = w0pack + (size_t)HID * IN_DIM;     // 512*64
    float* pnorm = (float*)(w1pack + (size_t)D_DIM * HID);      // 2048
    float* rowS = pnorm + P_N;                                  // 32768
    unsigned* rowKey = (unsigned*)(rowS + B_N);                 // 32768
    float* soft = (float*)(rowKey + B_N);                       // 2048
    float* scal = soft + P_N;                                   // 2
    float* vqpart = scal + 2;                                   // 512

    // zero rowS, rowKey, soft, scal (contiguous)
    hipMemsetAsync(rowS, 0, (size_t)(B_N * 2 + P_N + 2) * 4, stream);

    k_pack<<<(HID * (IN_DIM / 8) + 255) / 256, 256, 0, stream>>>(W0, w0pack, HID, IN_DIM / 8);
    k_pack<<<(D_DIM * (HID / 8) + 255) / 256, 256, 0, stream>>>(W1, w1pack, D_DIM, HID / 8);
    k_packrm<<<P_N * 64 / 256, 256, 0, stream>>>(protos, pb16, P_N);
    k_packmv<<<1024 * 64 / 256, 256, 0, stream>>>(Wmu, Wvar, wmv16);
    k_pnorm<<<P_N / 4, 256, 0, stream>>>(protos, pnorm);

    k_enc1<<<B_N / 128, 256, 0, stream>>>(x, w0pack, b0, h1b);
    k_enc2<<<B_N / 64, 256, 0, stream>>>(h1b, w1pack, b1, h2b);

    dim3 gmv(B_N / 128, 8);
    k_mv<<<gmv, 256, 0, stream>>>(h2b, wmv16, bmu, bvar, eps, out, lat16, scal);

    dim3 gvq(B_N / 128, 16);
    k_vq1<<<gvq, 256, 0, stream>>>(lat16, pb16, pnorm, rowS, rowKey);
    k_vq2<<<gvq, 256, 0, stream>>>(lat16, pb16, pnorm, rowS, soft);

    k_quant<<<B_N / 64, 256, 0, stream>>>(protos, rowKey, out, vqpart);
    k_final<<<1, 256, 0, stream>>>(soft, scal, vqpart, out);
}

// Round 8
// 382.643 us; speedup vs baseline: 3.5183x; 1.1877x over previous
//
#include <hip/hip_runtime.h>
#include <math.h>

#define B_N 32768
#define IN_DIM 1024
#define HID 64
#define D_DIM 512
#define P_N 2048

typedef __attribute__((ext_vector_type(8))) short s16x8;
typedef __attribute__((ext_vector_type(4))) float f32x4;

__device__ __forceinline__ unsigned short f2bf(float f) {
    unsigned u = __float_as_uint(f);
    return (unsigned short)((u + 0x7fffu + ((u >> 16) & 1u)) >> 16);
}
__device__ __forceinline__ float bf2f(unsigned short v) {
    return __uint_as_float(((unsigned)v) << 16);
}

// async global->LDS, 16B per lane; lds dest = wave-uniform base + lane*16
__device__ __forceinline__ void gl_lds(const void* gsrc, void* ldst) {
    __builtin_amdgcn_global_load_lds(
        (const __attribute__((address_space(1))) unsigned int*)gsrc,
        (__attribute__((address_space(3))) unsigned int*)ldst, 16, 0, 0);
}

// ---------------------------------------------------------------------------
// Pack fp32 [nrows, ncols] row-major -> bf16 MFMA-B-fragment-major (enc1/enc2)
// ---------------------------------------------------------------------------
__global__ __launch_bounds__(256) void k_pack(const float* __restrict__ src,
                                              unsigned short* __restrict__ dst,
                                              int nrows, int nk8) {
    int gid = blockIdx.x * 256 + threadIdx.x;
    if (gid >= nrows * nk8) return;
    int row = gid / nk8, k8 = gid % nk8;
    int K32 = k8 >> 2;
    int lane = (row & 15) | ((k8 & 3) << 4);
    int P16 = row >> 4;
    int nk32 = nk8 >> 2;
    const float* s = src + (size_t)row * (nk8 * 8) + k8 * 8;
    float4 x = *(const float4*)s;
    float4 y = *(const float4*)(s + 4);
    s16x8 o;
    o[0] = (short)f2bf(x.x); o[1] = (short)f2bf(x.y);
    o[2] = (short)f2bf(x.z); o[3] = (short)f2bf(x.w);
    o[4] = (short)f2bf(y.x); o[5] = (short)f2bf(y.y);
    o[6] = (short)f2bf(y.z); o[7] = (short)f2bf(y.w);
    ((s16x8*)dst)[((size_t)P16 * nk32 + K32) * 64 + lane] = o;
}

// ---------------------------------------------------------------------------
// Pack fp32 row-major -> bf16 row-major (protos -> pb16). nrows x 512.
// ---------------------------------------------------------------------------
__global__ __launch_bounds__(256) void k_packrm(const float* __restrict__ src,
                                                unsigned short* __restrict__ dst,
                                                int nrows) {
    int gid = blockIdx.x * 256 + threadIdx.x;
    if (gid >= nrows * 64) return;
    int row = gid >> 6, k8 = gid & 63;
    const float* s = src + (size_t)row * 512 + k8 * 8;
    float4 x = *(const float4*)s;
    float4 y = *(const float4*)(s + 4);
    s16x8 o;
    o[0] = (short)f2bf(x.x); o[1] = (short)f2bf(x.y);
    o[2] = (short)f2bf(x.z); o[3] = (short)f2bf(x.w);
    o[4] = (short)f2bf(y.x); o[5] = (short)f2bf(y.y);
    o[6] = (short)f2bf(y.z); o[7] = (short)f2bf(y.w);
    ((s16x8*)(dst))[(size_t)row * 64 + k8] = o;
}

// ---------------------------------------------------------------------------
// Pack Wmu/Wvar -> bf16 [1024][512], 16-row interleave:
// row r: g=r>>5, i=r&31; i<16 -> Wmu[g*16+i], else Wvar[g*16+i-16].
// Fragment n (16 rows) is then pure-mu (n even) or pure-var (n odd) for the
// SAME d-range -> epilogue needs no cross-lane exchange.
// ---------------------------------------------------------------------------
__global__ __launch_bounds__(256) void k_packmv(const float* __restrict__ Wmu,
                                                const float* __restrict__ Wvar,
                                                unsigned short* __restrict__ dst) {
    int gid = blockIdx.x * 256 + threadIdx.x;   // 1024*64
    int row = gid >> 6, k8 = gid & 63;
    int g = row >> 5, i = row & 31;
    const float* s = (i < 16 ? Wmu + (size_t)(g * 16 + i) * 512
                             : Wvar + (size_t)(g * 16 + i - 16) * 512) + k8 * 8;
    float4 x = *(const float4*)s;
    float4 y = *(const float4*)(s + 4);
    s16x8 o;
    o[0] = (short)f2bf(x.x); o[1] = (short)f2bf(x.y);
    o[2] = (short)f2bf(x.z); o[3] = (short)f2bf(x.w);
    o[4] = (short)f2bf(y.x); o[5] = (short)f2bf(y.y);
    o[6] = (short)f2bf(y.z); o[7] = (short)f2bf(y.w);
    ((s16x8*)(dst))[(size_t)row * 64 + k8] = o;
}

// ---------------------------------------------------------------------------
// K1 (MFMA): h1 = relu(x @ W0^T + b0)  [B,1024] -> [B,64] bf16 out
// ---------------------------------------------------------------------------
__global__ __launch_bounds__(256, 4) void k_enc1(const float* __restrict__ x,
                                                 const unsigned short* __restrict__ w0p,
                                                 const float* __restrict__ b0,
                                                 unsigned short* __restrict__ h1b) {
    __shared__ s16x8 As[2048];  // 128 rows x 128 bf16, 32 KB
    const int tid = threadIdx.x;
    const int l = tid & 63, wid = tid >> 6;
    const int bm = blockIdx.x * 128;
    const s16x8* w0p8 = (const s16x8*)w0p;

    const int srow = tid >> 1, ssub = tid & 1;
    const int srb = srow * 256, ssw = (srow & 7) << 4;

    const int klane = (l >> 4) << 4;
    const int sw = (l & 7) << 4;
    int aoff[2];
#pragma unroll
    for (int m = 0; m < 2; ++m) aoff[m] = (wid * 32 + m * 16 + (l & 15)) * 256;

    f32x4 acc[2][4];
#pragma unroll
    for (int m = 0; m < 2; ++m)
#pragma unroll
        for (int pf = 0; pf < 4; ++pf) acc[m][pf] = (f32x4)0.f;

    for (int kt = 0; kt < 8; ++kt) {
        const float* src = x + (size_t)(bm + srow) * IN_DIM + kt * 128 + ssub * 64;
#pragma unroll
        for (int it = 0; it < 8; ++it) {
            float4 a = *(const float4*)(src + it * 8);
            float4 b = *(const float4*)(src + it * 8 + 4);
            s16x8 o;
            o[0] = (short)f2bf(a.x); o[1] = (short)f2bf(a.y);
            o[2] = (short)f2bf(a.z); o[3] = (short)f2bf(a.w);
            o[4] = (short)f2bf(b.x); o[5] = (short)f2bf(b.y);
            o[6] = (short)f2bf(b.z); o[7] = (short)f2bf(b.w);
            int kbyte = ssub * 128 + it * 16;
            As[(srb + (kbyte ^ ssw)) >> 4] = o;
        }
        __syncthreads();
#pragma unroll
        for (int K32 = 0; K32 < 4; ++K32) {
            const int Kg = kt * 4 + K32;
            s16x8 b[4];
#pragma unroll
            for (int pf = 0; pf < 4; ++pf) b[pf] = w0p8[((size_t)pf * 32 + Kg) * 64 + l];
            const int kb = (K32 * 64 + klane) ^ sw;
            s16x8 a[2];
#pragma unroll
            for (int m = 0; m < 2; ++m) a[m] = As[(aoff[m] + kb) >> 4];
#pragma unroll
            for (int m = 0; m < 2; ++m)
#pragma unroll
                for (int pf = 0; pf < 4; ++pf)
                    acc[m][pf] = __builtin_amdgcn_mfma_f32_16x16x32_bf16(a[m], b[pf], acc[m][pf], 0, 0, 0);
        }
        __syncthreads();
    }
#pragma unroll
    for (int m = 0; m < 2; ++m)
#pragma unroll
        for (int pf = 0; pf < 4; ++pf) {
            const int c = pf * 16 + (l & 15);
            const float bb = b0[c];
#pragma unroll
            for (int j = 0; j < 4; ++j) {
                const int r = bm + wid * 32 + m * 16 + (l >> 4) * 4 + j;
                h1b[(size_t)r * HID + c] = f2bf(fmaxf(acc[m][pf][j] + bb, 0.f));
            }
        }
}

// ---------------------------------------------------------------------------
// K2 (MFMA): h2 = relu(h1 @ W1^T + b1)  [B,64] -> [B,512] bf16
// ---------------------------------------------------------------------------
__global__ __launch_bounds__(256, 4) void k_enc2(const unsigned short* __restrict__ h1b,
                                                 const unsigned short* __restrict__ w1p,
                                                 const float* __restrict__ b1,
                                                 unsigned short* __restrict__ h2b) {
    __shared__ s16x8 As[512];  // 64 rows x 64 bf16, 8 KB
    const int tid = threadIdx.x;
    const int l = tid & 63, wid = tid >> 6;
    const int bm = blockIdx.x * 64;
    const s16x8* w1p8 = (const s16x8*)w1p;

#pragma unroll
    for (int it = 0; it < 2; ++it) {
        int g = tid * 2 + it;
        int row = g >> 3, k8 = g & 7;
        s16x8 v = ((const s16x8*)(h1b + (size_t)(bm + row) * HID))[k8];
        As[(row * 128 + ((k8 * 16) ^ ((row & 7) << 4))) >> 4] = v;
    }
    __syncthreads();

    const int arow = wid * 16 + (l & 15);
    const int sw = (l & 7) << 4;
    const int klane = (l >> 4) << 4;
    s16x8 a[2];
#pragma unroll
    for (int K32 = 0; K32 < 2; ++K32)
        a[K32] = As[(arow * 128 + ((K32 * 64 + klane) ^ sw)) >> 4];

    const int r0 = bm + wid * 16 + (l >> 4) * 4;
#pragma unroll
    for (int ct = 0; ct < 4; ++ct) {
        f32x4 acc[8];
#pragma unroll
        for (int pf = 0; pf < 8; ++pf) acc[pf] = (f32x4)0.f;
#pragma unroll
        for (int K32 = 0; K32 < 2; ++K32)
#pragma unroll
            for (int pf = 0; pf < 8; ++pf) {
                s16x8 b = w1p8[(((size_t)(ct * 8 + pf)) * 2 + K32) * 64 + l];
                acc[pf] = __builtin_amdgcn_mfma_f32_16x16x32_bf16(a[K32], b, acc[pf], 0, 0, 0);
            }
#pragma unroll
        for (int pf = 0; pf < 8; ++pf) {
            const int c = ct * 128 + pf * 16 + (l & 15);
            const float bb = b1[c];
#pragma unroll
            for (int j = 0; j < 4; ++j)
                h2b[(size_t)(r0 + j) * D_DIM + c] = f2bf(fmaxf(acc[pf][j] + bb, 0.f));
        }
    }
}

// ===========================================================================
// m97-style GEMM core: BM=BN=128, BK=64, 256 thr / 4 waves, 32 KB LDS,
// global_load_lds staging for A and B (both row-major bf16, K-stride 512).
// ===========================================================================
#define GEMM_CORE(Aptr, Bptr)                                                  \
    __shared__ s16x8 A8[1024];                                                 \
    __shared__ s16x8 B8[1024];                                                 \
    const int tid = threadIdx.x;                                               \
    const int l = tid & 63, w = tid >> 6;                                      \
    const int bm = blockIdx.x * 128;                                           \
    const int bn = blockIdx.y * 128;                                           \
    const int wr = w >> 1, wc = w & 1;                                         \
    const int srow = l >> 3;                                                   \
    const int scol = (l & 7) * 8;                                              \
    f32x4 acc[4][4];                                                           \
    _Pragma("unroll") for (int m = 0; m < 4; ++m)                              \
        _Pragma("unroll") for (int n = 0; n < 4; ++n) acc[m][n] = (f32x4)0.f;  \
    for (int kt = 0; kt < 8; ++kt) {                                           \
        __syncthreads();                                                       \
        _Pragma("unroll") for (int i = 0; i < 4; ++i) {                        \
            const int rb = w * 32 + i * 8;                                     \
            gl_lds(Aptr + (size_t)(bm + rb + srow) * 512 + kt * 64 + scol,     \
                   (char*)A8 + rb * 128);                                      \
            gl_lds(Bptr + (size_t)(bn + rb + srow) * 512 + kt * 64 + scol,     \
                   (char*)B8 + rb * 128);                                      \
        }                                                                      \
        __syncthreads();                                                       \
        _Pragma("unroll") for (int K32 = 0; K32 < 2; ++K32) {                  \
            const int kb = K32 * 64 + (l >> 4) * 16;                           \
            s16x8 a[4], b[4];                                                  \
            _Pragma("unroll") for (int m = 0; m < 4; ++m)                      \
                a[m] = A8[((wr * 64 + m * 16 + (l & 15)) * 128 + kb) >> 4];    \
            _Pragma("unroll") for (int n = 0; n < 4; ++n)                      \
                b[n] = B8[((wc * 64 + n * 16 + (l & 15)) * 128 + kb) >> 4];    \
            _Pragma("unroll") for (int m = 0; m < 4; ++m)                      \
                _Pragma("unroll") for (int n = 0; n < 4; ++n)                  \
                    acc[m][n] = __builtin_amdgcn_mfma_f32_16x16x32_bf16(       \
                        a[m], b[n], acc[m][n], 0, 0, 0);                       \
        }                                                                      \
    }

// ---------------------------------------------------------------------------
// K3 (GEMM): mu/var (16-row-interleaved pack) + reparameterize + KL.
// Fragment n even = mu, n odd = var, same d = bn/2 + wc*32 + (n/2)*16 + col.
// All lanes active; no shuffles; lat16 only.
// ---------------------------------------------------------------------------
__global__ __launch_bounds__(256, 4) void k_mv(const unsigned short* __restrict__ h2b,
                                               const unsigned short* __restrict__ wmv16,
                                               const float* __restrict__ bmu,
                                               const float* __restrict__ bvar,
                                               const float* __restrict__ eps,
                                               unsigned short* __restrict__ lat16,
                                               float* __restrict__ div_acc) {
    GEMM_CORE(h2b, wmv16)
    __shared__ float red[4];
    float kl = 0.f;
    const int dbase0 = (bn >> 1) + wc * 32;
#pragma unroll
    for (int m = 0; m < 4; ++m)
#pragma unroll
        for (int nn = 0; nn < 2; ++nn) {
            const int d = dbase0 + nn * 16 + (l & 15);
            const float bmv = bmu[d], bvv = bvar[d];
#pragma unroll
            for (int j = 0; j < 4; ++j) {
                const int r = bm + wr * 64 + m * 16 + (l >> 4) * 4 + j;
                float mu = acc[m][2 * nn][j] + bmv;
                float lv = acc[m][2 * nn + 1][j] + bvv;
                float la = fmaf(eps[(size_t)r * D_DIM + d], __expf(0.5f * lv), mu);
                lat16[(size_t)r * D_DIM + d] = f2bf(la);
                kl += mu * mu + __expf(lv) - lv - 1.f;
            }
        }
    kl *= 0.5f;
#pragma unroll
    for (int d = 1; d < 64; d <<= 1) kl += __shfl_xor(kl, d);
    if (l == 0) red[w] = kl;
    __syncthreads();
    if (tid == 0) atomicAdd(div_acc, red[0] + red[1] + red[2] + red[3]);
}

// ---------------------------------------------------------------------------
// K4a: pnorm[p] = sum_d protos[p,d]^2
// ---------------------------------------------------------------------------
__global__ __launch_bounds__(256) void k_pnorm(const float* __restrict__ protos,
                                               float* __restrict__ pnorm) {
    const int p = blockIdx.x * 4 + (threadIdx.x >> 6);
    const int lane = threadIdx.x & 63;
    const float* row = protos + (size_t)p * D_DIM;
    float4 v1 = *(const float4*)(row + lane * 8);
    float4 v2 = *(const float4*)(row + lane * 8 + 4);
    float s = v1.x * v1.x + v1.y * v1.y + v1.z * v1.z + v1.w * v1.w +
              v2.x * v2.x + v2.y * v2.y + v2.z * v2.z + v2.w * v2.w;
#pragma unroll
    for (int m = 1; m < 64; m <<= 1) s += __shfl_xor(s, m);
    if (lane == 0) pnorm[p] = s;
}

// ---------------------------------------------------------------------------
// K4 (GEMM sweep0): per-row sumexp + packed-key argmax via global atomics.
// ---------------------------------------------------------------------------
__global__ __launch_bounds__(256, 4) void k_vq1(const unsigned short* __restrict__ lat16,
                                                const unsigned short* __restrict__ pb16,
                                                const float* __restrict__ pnorm,
                                                float* __restrict__ rowS,
                                                unsigned* __restrict__ rowKey) {
    GEMM_CORE(lat16, pb16)
    float pn[4];
#pragma unroll
    for (int n = 0; n < 4; ++n) pn[n] = pnorm[bn + wc * 64 + n * 16 + (l & 15)];
#pragma unroll
    for (int m = 0; m < 4; ++m)
#pragma unroll
        for (int j = 0; j < 4; ++j) {
            float se = 0.f;
            unsigned key = 0u;
#pragma unroll
            for (int n = 0; n < 4; ++n) {
                const int p = bn + wc * 64 + n * 16 + (l & 15);
                float g = 2.f * acc[m][n][j] - pn[n];
                se += __expf(g);
                unsigned kk = (__float_as_uint(g + 16.0f) & 0xFFFFF800u) | (unsigned)(2047 - p);
                key = key > kk ? key : kk;
            }
#pragma unroll
            for (int d = 1; d < 16; d <<= 1) {
                se += __shfl_xor(se, d);
                unsigned ok = (unsigned)__shfl_xor((int)key, d);
                key = key > ok ? key : ok;
            }
            if ((l & 15) == 0) {
                const int row = bm + wr * 64 + m * 16 + (l >> 4) * 4 + j;
                atomicAdd(&rowS[row], se);
                atomicMax(&rowKey[row], key);
            }
        }
}

// ---------------------------------------------------------------------------
// K5 (GEMM sweep1): soft_acc[p] += sum_rows exp(g)/rowS[row].
// ---------------------------------------------------------------------------
__global__ __launch_bounds__(256, 4) void k_vq2(const unsigned short* __restrict__ lat16,
                                                const unsigned short* __restrict__ pb16,
                                                const float* __restrict__ pnorm,
                                                const float* __restrict__ rowS,
                                                float* __restrict__ soft_acc) {
    __shared__ float soft_l[128];
    if (threadIdx.x < 128) soft_l[threadIdx.x] = 0.f;
    GEMM_CORE(lat16, pb16)
    float pn[4];
#pragma unroll
    for (int n = 0; n < 4; ++n) pn[n] = pnorm[bn + wc * 64 + n * 16 + (l & 15)];
    float cs[4] = {0.f, 0.f, 0.f, 0.f};
#pragma unroll
    for (int m = 0; m < 4; ++m)
#pragma unroll
        for (int j = 0; j < 4; ++j) {
            const int row = bm + wr * 64 + m * 16 + (l >> 4) * 4 + j;
            const float is = 1.0f / rowS[row];
#pragma unroll
            for (int n = 0; n < 4; ++n) {
                float g = 2.f * acc[m][n][j] - pn[n];
                cs[n] += __expf(g) * is;
            }
        }
#pragma unroll
    for (int n = 0; n < 4; ++n) {
        cs[n] += __shfl_xor(cs[n], 16);
        cs[n] += __shfl_xor(cs[n], 32);
    }
    if (l < 16) {
#pragma unroll
        for (int n = 0; n < 4; ++n) atomicAdd(&soft_l[wc * 64 + n * 16 + l], cs[n]);
    }
    __syncthreads();
    if (tid < 128) atomicAdd(&soft_acc[bn + tid], soft_l[tid]);
}

// ---------------------------------------------------------------------------
// K6: out[r,:] = protos[idx[r],:] + vq partials (reads lat16; no atomics).
// ---------------------------------------------------------------------------
__global__ __launch_bounds__(256) void k_quant(const float* __restrict__ protos,
                                               const unsigned* __restrict__ rowKey,
                                               const unsigned short* __restrict__ lat16,
                                               float* __restrict__ out,
                                               float* __restrict__ vq_part) {
    const int tid = threadIdx.x;
    const int l = tid & 63, wid = tid >> 6;
    const int base = blockIdx.x * 64;
    float s = 0.f;
#pragma unroll
    for (int it = 0; it < 16; ++it) {
        const int r = base + it * 4 + wid;
        const int p = 2047 - (int)(rowKey[r] & 2047u);
        const float4* qp = (const float4*)(protos + (size_t)p * D_DIM);
        float4* op = (float4*)(out + (size_t)r * D_DIM);
        s16x8 lv = ((const s16x8*)(lat16 + (size_t)r * D_DIM))[l];
        float4 q1 = qp[l * 2], q2 = qp[l * 2 + 1];
        float d0 = q1.x - bf2f((unsigned short)lv[0]);
        float d1 = q1.y - bf2f((unsigned short)lv[1]);
        float d2 = q1.z - bf2f((unsigned short)lv[2]);
        float d3 = q1.w - bf2f((unsigned short)lv[3]);
        float d4 = q2.x - bf2f((unsigned short)lv[4]);
        float d5 = q2.y - bf2f((unsigned short)lv[5]);
        float d6 = q2.z - bf2f((unsigned short)lv[6]);
        float d7 = q2.w - bf2f((unsigned short)lv[7]);
        s += d0 * d0 + d1 * d1 + d2 * d2 + d3 * d3 +
             d4 * d4 + d5 * d5 + d6 * d6 + d7 * d7;
        op[l * 2] = q1; op[l * 2 + 1] = q2;
    }
#pragma unroll
    for (int m = 1; m < 64; m <<= 1) s += __shfl_xor(s, m);
    __shared__ float red[4];
    if (l == 0) red[wid] = s;
    __syncthreads();
    if (tid == 0) vq_part[blockIdx.x] = red[0] + red[1] + red[2] + red[3];
}

// ---------------------------------------------------------------------------
// K7: finalize scalars.
// ---------------------------------------------------------------------------
__global__ __launch_bounds__(256) void k_final(const float* __restrict__ soft_acc,
                                               const float* __restrict__ scal,
                                               const float* __restrict__ vq_part,
                                               float* __restrict__ out) {
    const int tid = threadIdx.x;
    __shared__ float red[256];
    float vals[8];
    float s = 0.f;
#pragma unroll
    for (int i = 0; i < 8; ++i) {
        float v = soft_acc[tid * 8 + i] * (1.0f / B_N) + 1e-6f;
        vals[i] = v;
        s += v;
    }
    red[tid] = s;
    __syncthreads();
    for (int off = 128; off > 0; off >>= 1) {
        if (tid < off) red[tid] += red[tid + off];
        __syncthreads();
    }
    float norm = red[0];
    __syncthreads();
    float e = 0.f;
#pragma unroll
    for (int i = 0; i < 8; ++i) {
        float p = vals[i] / norm;
        e -= p * __logf(p);
    }
    red[tid] = e;
    __syncthreads();
    for (int off = 128; off > 0; off >>= 1) {
        if (tid < off) red[tid] += red[tid + off];
        __syncthreads();
    }
    float ent = red[0];
    __syncthreads();
    red[tid] = vq_part[tid] + vq_part[tid + 256];
    __syncthreads();
    for (int off = 128; off > 0; off >>= 1) {
        if (tid < off) red[tid] += red[tid + off];
        __syncthreads();
    }
    if (tid == 0) {
        float div = scal[0] * (1.0f / B_N);
        float vq = red[0] * (1.0f / ((float)B_N * (float)D_DIM));
        float vq_loss = 1.25f * vq + 0.1f * ent;
        float total = 0.01f * div + vq_loss;
        out[(size_t)B_N * D_DIM] = total;
        out[(size_t)B_N * D_DIM + 1] = div;
    }
}

// ---------------------------------------------------------------------------
extern "C" void kernel_launch(void* const* d_in, const int* in_sizes, int n_in,
                              void* d_out, int out_size, void* d_ws, size_t ws_size,
                              hipStream_t stream) {
    const float* x = (const float*)d_in[0];
    const float* W0 = (const float*)d_in[1];
    const float* b0 = (const float*)d_in[2];
    const float* W1 = (const float*)d_in[3];
    const float* b1 = (const float*)d_in[4];
    const float* Wmu = (const float*)d_in[5];
    const float* bmu = (const float*)d_in[6];
    const float* Wvar = (const float*)d_in[7];
    const float* bvar = (const float*)d_in[8];
    const float* protos = (const float*)d_in[9];
    const float* eps = (const float*)d_in[10];
    float* out = (float*)d_out;

    unsigned short* wsp = (unsigned short*)d_ws;
    unsigned short* h1b = wsp;                                  // B*64 bf16
    unsigned short* h2b = h1b + (size_t)B_N * HID;              // B*512
    unsigned short* lat16 = h2b + (size_t)B_N * D_DIM;          // B*512
    unsigned short* pb16 = lat16 + (size_t)B_N * D_DIM;         // 2048*512
    unsigned short* wmv16 = pb16 + (size_t)P_N * D_DIM;         // 1024*512
    unsigned short* w0pack = wmv16 + (size_t)2 * D_DIM * D_DIM; // 64*1024
    unsigned short* w1pack = w0pack + (size_t)HID * IN_DIM;     // 512*64
    float* pnorm = (float*)(w1pack + (size_t)D_DIM * HID);      // 2048
    float* rowS = pnorm + P_N;                                  // 32768
    unsigned* rowKey = (unsigned*)(rowS + B_N);                 // 32768
    float* soft = (float*)(rowKey + B_N);                       // 2048
    float* scal = soft + P_N;                                   // 2
    float* vqpart = scal + 2;                                   // 512

    // zero rowS, rowKey, soft, scal (contiguous)
    hipMemsetAsync(rowS, 0, (size_t)(B_N * 2 + P_N + 2) * 4, stream);

    k_pack<<<(HID * (IN_DIM / 8) + 255) / 256, 256, 0, stream>>>(W0, w0pack, HID, IN_DIM / 8);
    k_pack<<<(D_DIM * (HID / 8) + 255) / 256, 256, 0, stream>>>(W1, w1pack, D_DIM, HID / 8);
    k_packrm<<<P_N * 64 / 256, 256, 0, stream>>>(protos, pb16, P_N);
    k_packmv<<<1024 * 64 / 256, 256, 0, stream>>>(Wmu, Wvar, wmv16);
    k_pnorm<<<P_N / 4, 256, 0, stream>>>(protos, pnorm);

    k_enc1<<<B_N / 128, 256, 0, stream>>>(x, w0pack, b0, h1b);
    k_enc2<<<B_N / 64, 256, 0, stream>>>(h1b, w1pack, b1, h2b);

    dim3 gmv(B_N / 128, 8);
    k_mv<<<gmv, 256, 0, stream>>>(h2b, wmv16, bmu, bvar, eps, lat16, scal);

    dim3 gvq(B_N / 128, 16);
    k_vq1<<<gvq, 256, 0, stream>>>(lat16, pb16, pnorm, rowS, rowKey);
    k_vq2<<<gvq, 256, 0, stream>>>(lat16, pb16, pnorm, rowS, soft);

    k_quant<<<B_N / 64, 256, 0, stream>>>(protos, rowKey, lat16, out, vqpart);
    k_final<<<1, 256, 0, stream>>>(soft, scal, vqpart, out);
}

// Round 9
// 315.957 us; speedup vs baseline: 4.2609x; 1.2111x over previous
//
#include <hip/hip_runtime.h>
#include <math.h>

#define B_N 32768
#define IN_DIM 1024
#define HID 64
#define D_DIM 512
#define P_N 2048

typedef __attribute__((ext_vector_type(8))) short s16x8;
typedef __attribute__((ext_vector_type(4))) float f32x4;

__device__ __forceinline__ unsigned short f2bf(float f) {
    unsigned u = __float_as_uint(f);
    return (unsigned short)((u + 0x7fffu + ((u >> 16) & 1u)) >> 16);
}
__device__ __forceinline__ float bf2f(unsigned short v) {
    return __uint_as_float(((unsigned)v) << 16);
}

// async global->LDS, 16B per lane; lds dest = wave-uniform base + lane*16
__device__ __forceinline__ void gl_lds(const void* gsrc, void* ldst) {
    __builtin_amdgcn_global_load_lds(
        (const __attribute__((address_space(1))) unsigned int*)gsrc,
        (__attribute__((address_space(3))) unsigned int*)ldst, 16, 0, 0);
}

// ---------------------------------------------------------------------------
// Pack fp32 [nrows, ncols] row-major -> bf16 MFMA-B-fragment-major (enc1/enc2)
// ---------------------------------------------------------------------------
__global__ __launch_bounds__(256) void k_pack(const float* __restrict__ src,
                                              unsigned short* __restrict__ dst,
                                              int nrows, int nk8) {
    int gid = blockIdx.x * 256 + threadIdx.x;
    if (gid >= nrows * nk8) return;
    int row = gid / nk8, k8 = gid % nk8;
    int K32 = k8 >> 2;
    int lane = (row & 15) | ((k8 & 3) << 4);
    int P16 = row >> 4;
    int nk32 = nk8 >> 2;
    const float* s = src + (size_t)row * (nk8 * 8) + k8 * 8;
    float4 x = *(const float4*)s;
    float4 y = *(const float4*)(s + 4);
    s16x8 o;
    o[0] = (short)f2bf(x.x); o[1] = (short)f2bf(x.y);
    o[2] = (short)f2bf(x.z); o[3] = (short)f2bf(x.w);
    o[4] = (short)f2bf(y.x); o[5] = (short)f2bf(y.y);
    o[6] = (short)f2bf(y.z); o[7] = (short)f2bf(y.w);
    ((s16x8*)dst)[((size_t)P16 * nk32 + K32) * 64 + lane] = o;
}

// ---------------------------------------------------------------------------
// Pack fp32 row-major -> bf16 row-major (protos -> pb16). nrows x 512.
// ---------------------------------------------------------------------------
__global__ __launch_bounds__(256) void k_packrm(const float* __restrict__ src,
                                                unsigned short* __restrict__ dst,
                                                int nrows) {
    int gid = blockIdx.x * 256 + threadIdx.x;
    if (gid >= nrows * 64) return;
    int row = gid >> 6, k8 = gid & 63;
    const float* s = src + (size_t)row * 512 + k8 * 8;
    float4 x = *(const float4*)s;
    float4 y = *(const float4*)(s + 4);
    s16x8 o;
    o[0] = (short)f2bf(x.x); o[1] = (short)f2bf(x.y);
    o[2] = (short)f2bf(x.z); o[3] = (short)f2bf(x.w);
    o[4] = (short)f2bf(y.x); o[5] = (short)f2bf(y.y);
    o[6] = (short)f2bf(y.z); o[7] = (short)f2bf(y.w);
    ((s16x8*)(dst))[(size_t)row * 64 + k8] = o;
}

// ---------------------------------------------------------------------------
// Pack Wmu/Wvar -> bf16 [1024][512], 16-row interleave.
// ---------------------------------------------------------------------------
__global__ __launch_bounds__(256) void k_packmv(const float* __restrict__ Wmu,
                                                const float* __restrict__ Wvar,
                                                unsigned short* __restrict__ dst) {
    int gid = blockIdx.x * 256 + threadIdx.x;   // 1024*64
    int row = gid >> 6, k8 = gid & 63;
    int g = row >> 5, i = row & 31;
    const float* s = (i < 16 ? Wmu + (size_t)(g * 16 + i) * 512
                             : Wvar + (size_t)(g * 16 + i - 16) * 512) + k8 * 8;
    float4 x = *(const float4*)s;
    float4 y = *(const float4*)(s + 4);
    s16x8 o;
    o[0] = (short)f2bf(x.x); o[1] = (short)f2bf(x.y);
    o[2] = (short)f2bf(x.z); o[3] = (short)f2bf(x.w);
    o[4] = (short)f2bf(y.x); o[5] = (short)f2bf(y.y);
    o[6] = (short)f2bf(y.z); o[7] = (short)f2bf(y.w);
    ((s16x8*)(dst))[(size_t)row * 64 + k8] = o;
}

// ---------------------------------------------------------------------------
// K1 (MFMA): h1 = relu(x @ W0^T + b0)  [B,1024] -> [B,64] bf16 out
// ---------------------------------------------------------------------------
__global__ __launch_bounds__(256, 4) void k_enc1(const float* __restrict__ x,
                                                 const unsigned short* __restrict__ w0p,
                                                 const float* __restrict__ b0,
                                                 unsigned short* __restrict__ h1b) {
    __shared__ s16x8 As[2048];  // 128 rows x 128 bf16, 32 KB
    const int tid = threadIdx.x;
    const int l = tid & 63, wid = tid >> 6;
    const int bm = blockIdx.x * 128;
    const s16x8* w0p8 = (const s16x8*)w0p;

    const int srow = tid >> 1, ssub = tid & 1;
    const int srb = srow * 256, ssw = (srow & 7) << 4;

    const int klane = (l >> 4) << 4;
    const int sw = (l & 7) << 4;
    int aoff[2];
#pragma unroll
    for (int m = 0; m < 2; ++m) aoff[m] = (wid * 32 + m * 16 + (l & 15)) * 256;

    f32x4 acc[2][4];
#pragma unroll
    for (int m = 0; m < 2; ++m)
#pragma unroll
        for (int pf = 0; pf < 4; ++pf) acc[m][pf] = (f32x4)0.f;

    for (int kt = 0; kt < 8; ++kt) {
        const float* src = x + (size_t)(bm + srow) * IN_DIM + kt * 128 + ssub * 64;
#pragma unroll
        for (int it = 0; it < 8; ++it) {
            float4 a = *(const float4*)(src + it * 8);
            float4 b = *(const float4*)(src + it * 8 + 4);
            s16x8 o;
            o[0] = (short)f2bf(a.x); o[1] = (short)f2bf(a.y);
            o[2] = (short)f2bf(a.z); o[3] = (short)f2bf(a.w);
            o[4] = (short)f2bf(b.x); o[5] = (short)f2bf(b.y);
            o[6] = (short)f2bf(b.z); o[7] = (short)f2bf(b.w);
            int kbyte = ssub * 128 + it * 16;
            As[(srb + (kbyte ^ ssw)) >> 4] = o;
        }
        __syncthreads();
#pragma unroll
        for (int K32 = 0; K32 < 4; ++K32) {
            const int Kg = kt * 4 + K32;
            s16x8 b[4];
#pragma unroll
            for (int pf = 0; pf < 4; ++pf) b[pf] = w0p8[((size_t)pf * 32 + Kg) * 64 + l];
            const int kb = (K32 * 64 + klane) ^ sw;
            s16x8 a[2];
#pragma unroll
            for (int m = 0; m < 2; ++m) a[m] = As[(aoff[m] + kb) >> 4];
#pragma unroll
            for (int m = 0; m < 2; ++m)
#pragma unroll
                for (int pf = 0; pf < 4; ++pf)
                    acc[m][pf] = __builtin_amdgcn_mfma_f32_16x16x32_bf16(a[m], b[pf], acc[m][pf], 0, 0, 0);
        }
        __syncthreads();
    }
#pragma unroll
    for (int m = 0; m < 2; ++m)
#pragma unroll
        for (int pf = 0; pf < 4; ++pf) {
            const int c = pf * 16 + (l & 15);
            const float bb = b0[c];
#pragma unroll
            for (int j = 0; j < 4; ++j) {
                const int r = bm + wid * 32 + m * 16 + (l >> 4) * 4 + j;
                h1b[(size_t)r * HID + c] = f2bf(fmaxf(acc[m][pf][j] + bb, 0.f));
            }
        }
}

// ---------------------------------------------------------------------------
// K2 (MFMA): h2 = relu(h1 @ W1^T + b1)  [B,64] -> [B,512] bf16
// ---------------------------------------------------------------------------
__global__ __launch_bounds__(256, 4) void k_enc2(const unsigned short* __restrict__ h1b,
                                                 const unsigned short* __restrict__ w1p,
                                                 const float* __restrict__ b1,
                                                 unsigned short* __restrict__ h2b) {
    __shared__ s16x8 As[512];  // 64 rows x 64 bf16, 8 KB
    const int tid = threadIdx.x;
    const int l = tid & 63, wid = tid >> 6;
    const int bm = blockIdx.x * 64;
    const s16x8* w1p8 = (const s16x8*)w1p;

#pragma unroll
    for (int it = 0; it < 2; ++it) {
        int g = tid * 2 + it;
        int row = g >> 3, k8 = g & 7;
        s16x8 v = ((const s16x8*)(h1b + (size_t)(bm + row) * HID))[k8];
        As[(row * 128 + ((k8 * 16) ^ ((row & 7) << 4))) >> 4] = v;
    }
    __syncthreads();

    const int arow = wid * 16 + (l & 15);
    const int sw = (l & 7) << 4;
    const int klane = (l >> 4) << 4;
    s16x8 a[2];
#pragma unroll
    for (int K32 = 0; K32 < 2; ++K32)
        a[K32] = As[(arow * 128 + ((K32 * 64 + klane) ^ sw)) >> 4];

    const int r0 = bm + wid * 16 + (l >> 4) * 4;
#pragma unroll
    for (int ct = 0; ct < 4; ++ct) {
        f32x4 acc[8];
#pragma unroll
        for (int pf = 0; pf < 8; ++pf) acc[pf] = (f32x4)0.f;
#pragma unroll
        for (int K32 = 0; K32 < 2; ++K32)
#pragma unroll
            for (int pf = 0; pf < 8; ++pf) {
                s16x8 b = w1p8[(((size_t)(ct * 8 + pf)) * 2 + K32) * 64 + l];
                acc[pf] = __builtin_amdgcn_mfma_f32_16x16x32_bf16(a[K32], b, acc[pf], 0, 0, 0);
            }
#pragma unroll
        for (int pf = 0; pf < 8; ++pf) {
            const int c = ct * 128 + pf * 16 + (l & 15);
            const float bb = b1[c];
#pragma unroll
            for (int j = 0; j < 4; ++j)
                h2b[(size_t)(r0 + j) * D_DIM + c] = f2bf(fmaxf(acc[pf][j] + bb, 0.f));
        }
    }
}

// ===========================================================================
// m97-style GEMM core + T2 source-swizzle: BM=BN=128, BK=64, 256 thr/4 waves.
// LDS linear dest (gl_lds requirement); global SOURCE chunk pre-swizzled by
// (l&7)^((l>>3)&7); reads XOR byte addr with ((l&7)<<4) (row&7 == l&7 for all
// fragment rows). 16-way bank conflict -> <=2-way.
// ===========================================================================
#define GEMM_CORE(Aptr, Bptr)                                                  \
    __shared__ s16x8 A8[1024];                                                 \
    __shared__ s16x8 B8[1024];                                                 \
    const int tid = threadIdx.x;                                               \
    const int l = tid & 63, w = tid >> 6;                                      \
    const int bm = blockIdx.x * 128;                                           \
    const int bn = blockIdx.y * 128;                                           \
    const int wr = w >> 1, wc = w & 1;                                         \
    const int srow = l >> 3;                                                   \
    const int scol = (((l & 7) ^ ((l >> 3) & 7)) * 8);                         \
    f32x4 acc[4][4];                                                           \
    _Pragma("unroll") for (int m = 0; m < 4; ++m)                              \
        _Pragma("unroll") for (int n = 0; n < 4; ++n) acc[m][n] = (f32x4)0.f;  \
    for (int kt = 0; kt < 8; ++kt) {                                           \
        __syncthreads();                                                       \
        _Pragma("unroll") for (int i = 0; i < 4; ++i) {                        \
            const int rb = w * 32 + i * 8;                                     \
            gl_lds(Aptr + (size_t)(bm + rb + srow) * 512 + kt * 64 + scol,     \
                   (char*)A8 + rb * 128);                                      \
            gl_lds(Bptr + (size_t)(bn + rb + srow) * 512 + kt * 64 + scol,     \
                   (char*)B8 + rb * 128);                                      \
        }                                                                      \
        __syncthreads();                                                       \
        _Pragma("unroll") for (int K32 = 0; K32 < 2; ++K32) {                  \
            const int kb = (K32 * 64 + (l >> 4) * 16) ^ ((l & 7) << 4);        \
            s16x8 a[4], b[4];                                                  \
            _Pragma("unroll") for (int m = 0; m < 4; ++m)                      \
                a[m] = A8[((wr * 64 + m * 16 + (l & 15)) * 128 + kb) >> 4];    \
            _Pragma("unroll") for (int n = 0; n < 4; ++n)                      \
                b[n] = B8[((wc * 64 + n * 16 + (l & 15)) * 128 + kb) >> 4];    \
            _Pragma("unroll") for (int m = 0; m < 4; ++m)                      \
                _Pragma("unroll") for (int n = 0; n < 4; ++n)                  \
                    acc[m][n] = __builtin_amdgcn_mfma_f32_16x16x32_bf16(       \
                        a[m], b[n], acc[m][n], 0, 0, 0);                       \
        }                                                                      \
    }

// ---------------------------------------------------------------------------
// K3 (GEMM): mu/var (16-row-interleaved pack) + reparameterize + KL.
// ---------------------------------------------------------------------------
__global__ __launch_bounds__(256, 4) void k_mv(const unsigned short* __restrict__ h2b,
                                               const unsigned short* __restrict__ wmv16,
                                               const float* __restrict__ bmu,
                                               const float* __restrict__ bvar,
                                               const float* __restrict__ eps,
                                               unsigned short* __restrict__ lat16,
                                               float* __restrict__ div_acc) {
    GEMM_CORE(h2b, wmv16)
    __shared__ float red[4];
    float kl = 0.f;
    const int dbase0 = (bn >> 1) + wc * 32;
#pragma unroll
    for (int m = 0; m < 4; ++m)
#pragma unroll
        for (int nn = 0; nn < 2; ++nn) {
            const int d = dbase0 + nn * 16 + (l & 15);
            const float bmv = bmu[d], bvv = bvar[d];
#pragma unroll
            for (int j = 0; j < 4; ++j) {
                const int r = bm + wr * 64 + m * 16 + (l >> 4) * 4 + j;
                float mu = acc[m][2 * nn][j] + bmv;
                float lv = acc[m][2 * nn + 1][j] + bvv;
                float la = fmaf(eps[(size_t)r * D_DIM + d], __expf(0.5f * lv), mu);
                lat16[(size_t)r * D_DIM + d] = f2bf(la);
                kl += mu * mu + __expf(lv) - lv - 1.f;
            }
        }
    kl *= 0.5f;
#pragma unroll
    for (int d = 1; d < 64; d <<= 1) kl += __shfl_xor(kl, d);
    if (l == 0) red[w] = kl;
    __syncthreads();
    if (tid == 0) atomicAdd(div_acc, red[0] + red[1] + red[2] + red[3]);
}

// ---------------------------------------------------------------------------
// K4a: pnorm[p] = sum_d protos[p,d]^2
// ---------------------------------------------------------------------------
__global__ __launch_bounds__(256) void k_pnorm(const float* __restrict__ protos,
                                               float* __restrict__ pnorm) {
    const int p = blockIdx.x * 4 + (threadIdx.x >> 6);
    const int lane = threadIdx.x & 63;
    const float* row = protos + (size_t)p * D_DIM;
    float4 v1 = *(const float4*)(row + lane * 8);
    float4 v2 = *(const float4*)(row + lane * 8 + 4);
    float s = v1.x * v1.x + v1.y * v1.y + v1.z * v1.z + v1.w * v1.w +
              v2.x * v2.x + v2.y * v2.y + v2.z * v2.z + v2.w * v2.w;
#pragma unroll
    for (int m = 1; m < 64; m <<= 1) s += __shfl_xor(s, m);
    if (lane == 0) pnorm[p] = s;
}

// ---------------------------------------------------------------------------
// K4 (GEMM sweep0): per-row sumexp + packed-key argmax via global atomics,
// AND store exp(g) as bf16 in fragment order (coalesced 16B/lane) so the
// soft-assign pass never redoes the GEMM.
// Unit layout: gdst8[ ((by&7)*256 + bx)*8*256 + (m*2+h)*256 + tid ]
//   h=0: {n0j0..n0j3, n1j0..n1j3}, h=1: {n2..., n3...}
// ---------------------------------------------------------------------------
__global__ __launch_bounds__(256, 4) void k_vq1(const unsigned short* __restrict__ lat16,
                                                const unsigned short* __restrict__ pb16,
                                                const float* __restrict__ pnorm,
                                                float* __restrict__ rowS,
                                                unsigned* __restrict__ rowKey,
                                                unsigned short* __restrict__ gA,
                                                unsigned short* __restrict__ gB) {
    GEMM_CORE(lat16, pb16)
    float pn[4];
#pragma unroll
    for (int n = 0; n < 4; ++n) pn[n] = pnorm[bn + wc * 64 + n * 16 + (l & 15)];
    s16x8* gd8 = (s16x8*)((blockIdx.y < 8) ? gA : gB);
    const size_t gbase = ((size_t)((blockIdx.y & 7) * 256 + blockIdx.x) * 8) * 256;
#pragma unroll
    for (int m = 0; m < 4; ++m) {
        float gv[4][4], ev[4][4];
#pragma unroll
        for (int n = 0; n < 4; ++n)
#pragma unroll
            for (int j = 0; j < 4; ++j) {
                gv[n][j] = 2.f * acc[m][n][j] - pn[n];
                ev[n][j] = __expf(gv[n][j]);
            }
        s16x8 u0, u1;
#pragma unroll
        for (int j = 0; j < 4; ++j) {
            u0[j] = (short)f2bf(ev[0][j]); u0[4 + j] = (short)f2bf(ev[1][j]);
            u1[j] = (short)f2bf(ev[2][j]); u1[4 + j] = (short)f2bf(ev[3][j]);
        }
        gd8[gbase + (size_t)(m * 2 + 0) * 256 + tid] = u0;
        gd8[gbase + (size_t)(m * 2 + 1) * 256 + tid] = u1;
#pragma unroll
        for (int j = 0; j < 4; ++j) {
            float se = ev[0][j] + ev[1][j] + ev[2][j] + ev[3][j];
            unsigned key = 0u;
#pragma unroll
            for (int n = 0; n < 4; ++n) {
                const int p = bn + wc * 64 + n * 16 + (l & 15);
                unsigned kk = (__float_as_uint(gv[n][j] + 16.0f) & 0xFFFFF800u) | (unsigned)(2047 - p);
                key = key > kk ? key : kk;
            }
#pragma unroll
            for (int d = 1; d < 16; d <<= 1) {
                se += __shfl_xor(se, d);
                unsigned ok = (unsigned)__shfl_xor((int)key, d);
                key = key > ok ? key : ok;
            }
            if ((l & 15) == 0) {
                const int row = bm + wr * 64 + m * 16 + (l >> 4) * 4 + j;
                atomicAdd(&rowS[row], se);
                atomicMax(&rowKey[row], key);
            }
        }
    }
}

// ---------------------------------------------------------------------------
// K5 (streaming): soft_acc[p] += sum_rows exp(g)/rowS[row]; reads stored bf16
// exp(g) — no GEMM. Same grid/thread geometry as k_vq1 for index decode.
// ---------------------------------------------------------------------------
__global__ __launch_bounds__(256, 4) void k_vq2s(const unsigned short* __restrict__ gA,
                                                 const unsigned short* __restrict__ gB,
                                                 const float* __restrict__ rowS,
                                                 float* __restrict__ soft_acc) {
    __shared__ float soft_l[128];
    const int tid = threadIdx.x;
    const int l = tid & 63, w = tid >> 6;
    const int wr = w >> 1, wc = w & 1;
    const int bm = blockIdx.x * 128;
    const int bn = blockIdx.y * 128;
    if (tid < 128) soft_l[tid] = 0.f;
    __syncthreads();

    const s16x8* gs8 = (const s16x8*)((blockIdx.y < 8) ? gA : gB);
    const size_t gbase = ((size_t)((blockIdx.y & 7) * 256 + blockIdx.x) * 8) * 256;

    float is[4][4];
#pragma unroll
    for (int m = 0; m < 4; ++m)
#pragma unroll
        for (int j = 0; j < 4; ++j)
            is[m][j] = 1.0f / rowS[bm + wr * 64 + m * 16 + (l >> 4) * 4 + j];

    float cs[4] = {0.f, 0.f, 0.f, 0.f};
#pragma unroll
    for (int m = 0; m < 4; ++m) {
        s16x8 u0 = gs8[gbase + (size_t)(m * 2 + 0) * 256 + tid];
        s16x8 u1 = gs8[gbase + (size_t)(m * 2 + 1) * 256 + tid];
#pragma unroll
        for (int j = 0; j < 4; ++j) {
            cs[0] += bf2f((unsigned short)u0[j]) * is[m][j];
            cs[1] += bf2f((unsigned short)u0[4 + j]) * is[m][j];
            cs[2] += bf2f((unsigned short)u1[j]) * is[m][j];
            cs[3] += bf2f((unsigned short)u1[4 + j]) * is[m][j];
        }
    }
#pragma unroll
    for (int n = 0; n < 4; ++n) {
        cs[n] += __shfl_xor(cs[n], 16);
        cs[n] += __shfl_xor(cs[n], 32);
    }
    if (l < 16) {
#pragma unroll
        for (int n = 0; n < 4; ++n) atomicAdd(&soft_l[wc * 64 + n * 16 + l], cs[n]);
    }
    __syncthreads();
    if (tid < 128) atomicAdd(&soft_acc[bn + tid], soft_l[tid]);
}

// ---------------------------------------------------------------------------
// K6: out[r,:] = protos[idx[r],:] + vq partials (reads lat16; no atomics).
// ---------------------------------------------------------------------------
__global__ __launch_bounds__(256) void k_quant(const float* __restrict__ protos,
                                               const unsigned* __restrict__ rowKey,
                                               const unsigned short* __restrict__ lat16,
                                               float* __restrict__ out,
                                               float* __restrict__ vq_part) {
    const int tid = threadIdx.x;
    const int l = tid & 63, wid = tid >> 6;
    const int base = blockIdx.x * 64;
    float s = 0.f;
#pragma unroll
    for (int it = 0; it < 16; ++it) {
        const int r = base + it * 4 + wid;
        const int p = 2047 - (int)(rowKey[r] & 2047u);
        const float4* qp = (const float4*)(protos + (size_t)p * D_DIM);
        float4* op = (float4*)(out + (size_t)r * D_DIM);
        s16x8 lv = ((const s16x8*)(lat16 + (size_t)r * D_DIM))[l];
        float4 q1 = qp[l * 2], q2 = qp[l * 2 + 1];
        float d0 = q1.x - bf2f((unsigned short)lv[0]);
        float d1 = q1.y - bf2f((unsigned short)lv[1]);
        float d2 = q1.z - bf2f((unsigned short)lv[2]);
        float d3 = q1.w - bf2f((unsigned short)lv[3]);
        float d4 = q2.x - bf2f((unsigned short)lv[4]);
        float d5 = q2.y - bf2f((unsigned short)lv[5]);
        float d6 = q2.z - bf2f((unsigned short)lv[6]);
        float d7 = q2.w - bf2f((unsigned short)lv[7]);
        s += d0 * d0 + d1 * d1 + d2 * d2 + d3 * d3 +
             d4 * d4 + d5 * d5 + d6 * d6 + d7 * d7;
        op[l * 2] = q1; op[l * 2 + 1] = q2;
    }
#pragma unroll
    for (int m = 1; m < 64; m <<= 1) s += __shfl_xor(s, m);
    __shared__ float red[4];
    if (l == 0) red[wid] = s;
    __syncthreads();
    if (tid == 0) vq_part[blockIdx.x] = red[0] + red[1] + red[2] + red[3];
}

// ---------------------------------------------------------------------------
// K7: finalize scalars.
// ---------------------------------------------------------------------------
__global__ __launch_bounds__(256) void k_final(const float* __restrict__ soft_acc,
                                               const float* __restrict__ scal,
                                               const float* __restrict__ vq_part,
                                               float* __restrict__ out) {
    const int tid = threadIdx.x;
    __shared__ float red[256];
    float vals[8];
    float s = 0.f;
#pragma unroll
    for (int i = 0; i < 8; ++i) {
        float v = soft_acc[tid * 8 + i] * (1.0f / B_N) + 1e-6f;
        vals[i] = v;
        s += v;
    }
    red[tid] = s;
    __syncthreads();
    for (int off = 128; off > 0; off >>= 1) {
        if (tid < off) red[tid] += red[tid + off];
        __syncthreads();
    }
    float norm = red[0];
    __syncthreads();
    float e = 0.f;
#pragma unroll
    for (int i = 0; i < 8; ++i) {
        float p = vals[i] / norm;
        e -= p * __logf(p);
    }
    red[tid] = e;
    __syncthreads();
    for (int off = 128; off > 0; off >>= 1) {
        if (tid < off) red[tid] += red[tid + off];
        __syncthreads();
    }
    float ent = red[0];
    __syncthreads();
    red[tid] = vq_part[tid] + vq_part[tid + 256];
    __syncthreads();
    for (int off = 128; off > 0; off >>= 1) {
        if (tid < off) red[tid] += red[tid + off];
        __syncthreads();
    }
    if (tid == 0) {
        float div = scal[0] * (1.0f / B_N);
        float vq = red[0] * (1.0f / ((float)B_N * (float)D_DIM));
        float vq_loss = 1.25f * vq + 0.1f * ent;
        float total = 0.01f * div + vq_loss;
        out[(size_t)B_N * D_DIM] = total;
        out[(size_t)B_N * D_DIM + 1] = div;
    }
}

// ---------------------------------------------------------------------------
extern "C" void kernel_launch(void* const* d_in, const int* in_sizes, int n_in,
                              void* d_out, int out_size, void* d_ws, size_t ws_size,
                              hipStream_t stream) {
    const float* x = (const float*)d_in[0];
    const float* W0 = (const float*)d_in[1];
    const float* b0 = (const float*)d_in[2];
    const float* W1 = (const float*)d_in[3];
    const float* b1 = (const float*)d_in[4];
    const float* Wmu = (const float*)d_in[5];
    const float* bmu = (const float*)d_in[6];
    const float* Wvar = (const float*)d_in[7];
    const float* bvar = (const float*)d_in[8];
    const float* protos = (const float*)d_in[9];
    const float* eps = (const float*)d_in[10];
    float* out = (float*)d_out;

    // ws layout (~100.5 MB): persistent small stuff first, then the staging
    // region where gA (64 MB, written by k_vq1 AFTER h1b/h2b are dead) aliases
    // h1b/h2b and extends past them. gB = d_out (overwritten later by k_quant).
    unsigned short* wsp = (unsigned short*)d_ws;
    unsigned short* lat16 = wsp;                                 // B*512 = 32MB
    unsigned short* pb16 = lat16 + (size_t)B_N * D_DIM;          // 2MB
    unsigned short* wmv16 = pb16 + (size_t)P_N * D_DIM;          // 2MB
    unsigned short* w0pack = wmv16 + (size_t)2 * D_DIM * D_DIM;  // 128KB
    unsigned short* w1pack = w0pack + (size_t)HID * IN_DIM;      // 64KB
    float* pnorm = (float*)(w1pack + (size_t)D_DIM * HID);       // 8KB
    float* rowS = pnorm + P_N;                                   // 128KB
    unsigned* rowKey = (unsigned*)(rowS + B_N);                  // 128KB
    float* soft = (float*)(rowKey + B_N);                        // 8KB
    float* scal = soft + P_N;                                    // 8B
    float* vqpart = scal + 2;                                    // 2KB
    unsigned short* h1b = (unsigned short*)(vqpart + 512);       // 4MB
    unsigned short* h2b = h1b + (size_t)B_N * HID;               // 32MB
    unsigned short* gA = h1b;                                    // 64MB (alias; live after k_mv)
    unsigned short* gB = (unsigned short*)d_out;                 // 64MB (live until k_quant)

    // zero rowS, rowKey, soft, scal (contiguous)
    hipMemsetAsync(rowS, 0, (size_t)(B_N * 2 + P_N + 2) * 4, stream);

    k_pack<<<(HID * (IN_DIM / 8) + 255) / 256, 256, 0, stream>>>(W0, w0pack, HID, IN_DIM / 8);
    k_pack<<<(D_DIM * (HID / 8) + 255) / 256, 256, 0, stream>>>(W1, w1pack, D_DIM, HID / 8);
    k_packrm<<<P_N * 64 / 256, 256, 0, stream>>>(protos, pb16, P_N);
    k_packmv<<<1024 * 64 / 256, 256, 0, stream>>>(Wmu, Wvar, wmv16);
    k_pnorm<<<P_N / 4, 256, 0, stream>>>(protos, pnorm);

    k_enc1<<<B_N / 128, 256, 0, stream>>>(x, w0pack, b0, h1b);
    k_enc2<<<B_N / 64, 256, 0, stream>>>(h1b, w1pack, b1, h2b);

    dim3 gmv(B_N / 128, 8);
    k_mv<<<gmv, 256, 0, stream>>>(h2b, wmv16, bmu, bvar, eps, lat16, scal);

    dim3 gvq(B_N / 128, 16);
    k_vq1<<<gvq, 256, 0, stream>>>(lat16, pb16, pnorm, rowS, rowKey, gA, gB);
    k_vq2s<<<gvq, 256, 0, stream>>>(gA, gB, rowS, soft);

    k_quant<<<B_N / 64, 256, 0, stream>>>(protos, rowKey, lat16, out, vqpart);
    k_final<<<1, 256, 0, stream>>>(soft, scal, vqpart, out);
}